// Round 12
// baseline (1782.743 us; speedup 1.0000x reference)
//
#include <hip/hip_runtime.h>
#include <hip/hip_bf16.h>
#include <hip/hip_fp16.h>
#include <hip/hip_cooperative_groups.h>

namespace cg = cooperative_groups;

#define N_D 256
#define NBLK 832   // cooperative build grid; block->edge striding fixed by this

typedef __attribute__((ext_vector_type(8))) short bf16x8;
typedef __attribute__((ext_vector_type(4))) float f32x4;

// f32 -> bf16 round-to-nearest-even (finite inputs)
__device__ __forceinline__ unsigned short f2bf(float f) {
  union { float f; unsigned u; } c; c.f = f;
  unsigned u = c.u;
  return (unsigned short)((u + 0x7fffu + ((u >> 16) & 1u)) >> 16);
}
__device__ __forceinline__ float asf(unsigned u) {
  union { unsigned u; float f; } c; c.u = u;
  return c.f;
}
__device__ __forceinline__ int grp_of(int r, unsigned gmagic) {
  int g = (int)(((unsigned long long)(unsigned)r * gmagic) >> 37);
  return min(g, 7);
}

// ---------- 256-thread exclusive scan (device fn); out[n] = total ----------
__device__ void scan256(const int* __restrict__ in, int* __restrict__ out, int n) {
  __shared__ int swsum[4];
  __shared__ int carry_sh;
  const int tid = threadIdx.x;
  const int lane = tid & 63;
  const int wid = tid >> 6;
  if (tid == 0) carry_sh = 0;
  __syncthreads();
  for (int base = 0; base < n; base += 1024) {
    const int i0 = base + tid * 4;
    int4 v = make_int4(0, 0, 0, 0);
    if (i0 + 3 < n) v = *reinterpret_cast<const int4*>(in + i0);
    else {
      if (i0     < n) v.x = in[i0];
      if (i0 + 1 < n) v.y = in[i0 + 1];
      if (i0 + 2 < n) v.z = in[i0 + 2];
    }
    const int s1 = v.x, s2 = s1 + v.y, s3 = s2 + v.z, s4 = s3 + v.w;
    int ws = s4;
#pragma unroll
    for (int off = 1; off < 64; off <<= 1) {
      int o = __shfl_up(ws, off, 64);
      if (lane >= off) ws += o;
    }
    if (lane == 63) swsum[wid] = ws;
    __syncthreads();
    if (wid == 0) {
      int t = (lane < 4) ? swsum[lane] : 0;
#pragma unroll
      for (int off = 1; off < 4; off <<= 1) {
        int o = __shfl_up(t, off, 64);
        if (lane >= off) t += o;
      }
      if (lane < 4) swsum[lane] = t;
    }
    __syncthreads();
    const int carry = carry_sh;
    const int tbase = carry + (wid ? swsum[wid - 1] : 0) + ws - s4;  // exclusive
    if (i0     < n) out[i0]     = tbase;
    if (i0 + 1 < n) out[i0 + 1] = tbase + s1;
    if (i0 + 2 < n) out[i0 + 2] = tbase + s2;
    if (i0 + 3 < n) out[i0 + 3] = tbase + s3;
    __syncthreads();
    if (tid == 0) carry_sh = carry + swsum[3];
    __syncthreads();
  }
  if (tid == 0) out[n] = carry_sh;
}

// ---------- ONE cooperative kernel = memset + count + sum + scans +
//            scan_apply + partition + scatter (6 dispatches -> 1) ----------
__global__ __launch_bounds__(256) void coop_build(
    const int* __restrict__ rows, const int* __restrict__ cols,
    const float* __restrict__ vals,
    int* __restrict__ cnt8, int* __restrict__ cntT, int* __restrict__ cnts,
    int* __restrict__ bsum, int* __restrict__ bofs, int* __restrict__ pofsT,
    int* __restrict__ row_ptr, int* __restrict__ cursor,
    int2* __restrict__ part, unsigned* __restrict__ colpack,
    const float* __restrict__ W0, const float* __restrict__ W1,
    unsigned short* __restrict__ WT0, unsigned short* __restrict__ WT1,
    int n_edges, unsigned gmagic, int M, int Mb) {
  cg::grid_group grid = cg::this_grid();
  __shared__ int l8[8];
  __shared__ int wred[4];
  const int tid = threadIdx.x;
  const int bid = blockIdx.x;

  // --- phase 0: zero cnt8; transpose W0/W1 -> bf16 WT ---
  {
    const int zn = 8 * M;
    for (int i = bid * 256 + tid; i < zn; i += NBLK * 256) cnt8[i] = 0;
    for (int i = bid * 256 + tid; i < 2 * 256 * 256; i += NBLK * 256) {
      const int w = i >> 16, k = (i >> 8) & 255, n = i & 255;
      const float* W = w ? W1 : W0;
      unsigned short* WT = w ? WT1 : WT0;
      WT[(size_t)n * N_D + k] = f2bf(W[(size_t)k * N_D + n]);
    }
  }
  grid.sync();

  // --- phase A: row histogram (XCD-local replica cnt8[bid&7]) + cntT ---
  {
    if (tid < 8) l8[tid] = 0;
    __syncthreads();
    int* __restrict__ cnt = cnt8 + (size_t)(bid & 7) * M;
    for (int e = bid * 256 + tid; e < n_edges; e += NBLK * 256) {
      const int r = rows[e];
      atomicAdd(&cnt[r], 1);
      atomicAdd(&l8[grp_of(r, gmagic)], 1);
    }
    __syncthreads();
    if (tid < 8) cntT[tid * NBLK + bid] = l8[tid];
  }
  grid.sync();

  // --- phase B: cnts = sum of 8 replicas; bsum = per-256-chunk totals ---
  for (int c = bid; c < Mb; c += NBLK) {
    const int i = c * 256 + tid;
    int s = 0;
    if (i < M) {
#pragma unroll
      for (int k = 0; k < 8; ++k) s += cnt8[(size_t)k * M + i];
      cnts[i] = s;
    }
    int t = s;
#pragma unroll
    for (int off = 32; off; off >>= 1) t += __shfl_down(t, off, 64);
    if ((tid & 63) == 0) wred[tid >> 6] = t;
    __syncthreads();
    if (tid == 0) bsum[c] = wred[0] + wred[1] + wred[2] + wred[3];
    __syncthreads();
  }
  grid.sync();

  // --- phase C: two small exclusive scans ---
  if (bid == 0)      scan256(bsum, bofs, Mb);
  else if (bid == 1) scan256(cntT, pofsT, 8 * NBLK);
  grid.sync();

  // --- phase D: row_ptr/cursor = bofs[chunk] + intra-chunk exclusive scan ---
  for (int c = bid; c < Mb; c += NBLK) {
    const int lane = tid & 63;
    const int wid = tid >> 6;
    const int i = c * 256 + tid;
    const int v = (i < M) ? cnts[i] : 0;
    int s = v;
#pragma unroll
    for (int off = 1; off < 64; off <<= 1) {
      int o = __shfl_up(s, off, 64);
      if (lane >= off) s += o;
    }
    if (lane == 63) wred[wid] = s;
    __syncthreads();
    int add = 0;
    for (int k = 0; k < wid; ++k) add += wred[k];
    const int excl = bofs[c] + add + s - v;
    if (i < M) { row_ptr[i] = excl; cursor[i] = excl; }
    if (i == M) row_ptr[M] = bofs[Mb];
    __syncthreads();
  }
  grid.sync();

  // --- phase E: partition edges into 8 contiguous XCD-group segments ---
  {
    if (tid < 8) l8[tid] = pofsT[tid * NBLK + bid];
    __syncthreads();
    for (int e = bid * 256 + tid; e < n_edges; e += NBLK * 256) {
      const int r = rows[e];
      const int g = grp_of(r, gmagic);
      const int slot = atomicAdd(&l8[g], 1);
      const unsigned short hb = __half_as_ushort(__float2half_rn(vals[e] * 0.5f));
      int2 rv;
      rv.x = r;
      rv.y = (int)(((unsigned)cols[e] << 15) | ((unsigned)hb >> 1));
      part[slot] = rv;
    }
  }
  grid.sync();

  // --- phase F: scatter within XCD-local group (write-merge friendly) ---
  {
    const int g  = bid & 7;
    const int bk = bid >> 3;
    const int nbg = NBLK >> 3;
    const int s0 = pofsT[g * NBLK];
    const int s1 = pofsT[(g + 1) * NBLK];
    for (int i = s0 + bk * 256 + tid; i < s1; i += nbg * 256) {
      const int2 rv = part[i];
      const int pos = atomicAdd(&cursor[rv.x], 1);
      colpack[pos] = (unsigned)rv.y;
    }
  }
}

// ---------- SpMM, feature-sliced (round-6 config: MLP 8, inline decode) ------
template <bool RELU, bool F32OUT>
__global__ __launch_bounds__(256) void spmm_slice(
    const unsigned short* __restrict__ hin, const int* __restrict__ row_ptr,
    const unsigned* __restrict__ colpack, void* __restrict__ hout,
    int n_nodes) {
  const int slice = blockIdx.x & 3;
  const int lane = threadIdx.x & 63;
  const int half = lane >> 5;
  const int sub  = lane & 31;
  const int wgid = ((blockIdx.x >> 2) * 256 + threadIdx.x) >> 6;  // node-pair id
  const int node = wgid * 2 + half;
  const bool ok = node < n_nodes;
  int start = 0, end = 0;
  if (ok) { start = row_ptr[node]; end = row_ptr[node + 1]; }

  const unsigned* __restrict__ hinw = reinterpret_cast<const unsigned*>(hin);
  const int fofs = slice * 32 + sub;       // uint index within a 128-uint row
  const int sbase = half << 5;

  float acc0 = 0.f, acc1 = 0.f;

  for (int base = start; base < end; base += 32) {
    const int cnt = min(32, end - base);
    unsigned u = 0;                        // u=0 -> (col=0, val=0) dummy
    if (base + sub < end) u = __builtin_nontemporal_load(&colpack[base + sub]);
    for (int t = 0; t < cnt; t += 8) {
      unsigned hv[8];
      float v[8];
#pragma unroll
      for (int j = 0; j < 8; ++j) {
        const unsigned ue = (unsigned)__shfl((int)u, sbase + t + j, 64);
        const int c = (int)(ue >> 15);
        v[j] = __half2float(__ushort_as_half((unsigned short)(ue << 1)));
        hv[j] = hinw[(size_t)c * 128 + fofs];   // 8 independent 4B gathers
      }
#pragma unroll
      for (int j = 0; j < 8; ++j) {
        acc0 += v[j] * asf(hv[j] << 16);
        acc1 += v[j] * asf(hv[j] & 0xffff0000u);
      }
    }
  }
  if (ok) {
    if (RELU) { acc0 = fmaxf(acc0, 0.f); acc1 = fmaxf(acc1, 0.f); }
    if (F32OUT) {
      reinterpret_cast<float2*>(hout)[(size_t)node * 128 + fofs] =
          make_float2(acc0, acc1);
    } else {
      reinterpret_cast<unsigned*>(hout)[(size_t)node * 128 + fofs] =
          (unsigned)f2bf(acc0) | ((unsigned)f2bf(acc1) << 16);
    }
  }
}

// ---------- GEMM: 128 rows/block, 2 row-frags/wave x 16 col-frags ------------
template <bool AF32>
__global__ __launch_bounds__(256) void gemm3(
    const void* __restrict__ H, const unsigned short* __restrict__ WT,
    unsigned short* __restrict__ C, int M) {
  const int wave = threadIdx.x >> 6;
  const int lane = threadIdx.x & 63;
  const int m = lane & 15;
  const int p = lane >> 4;
  const int row0 = blockIdx.x * 128 + wave * 32;

  f32x4 acc0[16], acc1[16];
#pragma unroll
  for (int i = 0; i < 16; ++i) {
    acc0[i] = (f32x4){0.f, 0.f, 0.f, 0.f};
    acc1[i] = (f32x4){0.f, 0.f, 0.f, 0.f};
  }

  const int r0 = row0 + m;
  const int r1 = row0 + 16 + m;
  const bool ok0 = r0 < M, ok1 = r1 < M;

  for (int k0 = 0; k0 < N_D; k0 += 32) {
    bf16x8 a0 = {0,0,0,0,0,0,0,0}, a1 = {0,0,0,0,0,0,0,0};
    if (AF32) {
      if (ok0) {
        const float* ap = (const float*)H + (size_t)r0 * N_D + k0 + p * 8;
        const float4 f0 = *reinterpret_cast<const float4*>(ap);
        const float4 f1 = *reinterpret_cast<const float4*>(ap + 4);
        a0[0]=f2bf(f0.x); a0[1]=f2bf(f0.y); a0[2]=f2bf(f0.z); a0[3]=f2bf(f0.w);
        a0[4]=f2bf(f1.x); a0[5]=f2bf(f1.y); a0[6]=f2bf(f1.z); a0[7]=f2bf(f1.w);
      }
      if (ok1) {
        const float* ap = (const float*)H + (size_t)r1 * N_D + k0 + p * 8;
        const float4 f0 = *reinterpret_cast<const float4*>(ap);
        const float4 f1 = *reinterpret_cast<const float4*>(ap + 4);
        a1[0]=f2bf(f0.x); a1[1]=f2bf(f0.y); a1[2]=f2bf(f0.z); a1[3]=f2bf(f0.w);
        a1[4]=f2bf(f1.x); a1[5]=f2bf(f1.y); a1[6]=f2bf(f1.z); a1[7]=f2bf(f1.w);
      }
    } else {
      if (ok0) a0 = *reinterpret_cast<const bf16x8*>(
          (const unsigned short*)H + (size_t)r0 * N_D + k0 + p * 8);
      if (ok1) a1 = *reinterpret_cast<const bf16x8*>(
          (const unsigned short*)H + (size_t)r1 * N_D + k0 + p * 8);
    }
#pragma unroll
    for (int nt = 0; nt < 16; ++nt) {
      const bf16x8 b = *reinterpret_cast<const bf16x8*>(
          WT + (size_t)(nt * 16 + m) * N_D + k0 + p * 8);
      acc0[nt] = __builtin_amdgcn_mfma_f32_16x16x32_bf16(a0, b, acc0[nt], 0, 0, 0);
      acc1[nt] = __builtin_amdgcn_mfma_f32_16x16x32_bf16(a1, b, acc1[nt], 0, 0, 0);
    }
  }

  // C/D layout: col = lane&15 (=m), row = p*4 + rr within each 16x16 tile
#pragma unroll
  for (int nt = 0; nt < 16; ++nt) {
    const int col = nt * 16 + m;
#pragma unroll
    for (int rr = 0; rr < 4; ++rr) {
      const int ra = row0 + p * 4 + rr;
      const int rb = ra + 16;
      if (ra < M) C[(size_t)ra * N_D + col] = f2bf(acc0[nt][rr]);
      if (rb < M) C[(size_t)rb * N_D + col] = f2bf(acc1[nt][rr]);
    }
  }
}

extern "C" void kernel_launch(void* const* d_in, const int* in_sizes, int n_in,
                              void* d_out, int out_size, void* d_ws, size_t ws_size,
                              hipStream_t stream) {
  const float* x    = (const float*)d_in[0];
  const float* vals = (const float*)d_in[1];
  const float* W0   = (const float*)d_in[2];
  const float* W1   = (const float*)d_in[3];
  const int*   rows = (const int*)d_in[4];
  const int*   cols = (const int*)d_in[5];

  int n_edges = in_sizes[1];
  int M = in_sizes[0] / N_D;              // 100000
  const size_t n_feat = (size_t)M * N_D;  // 25.6M elements

  char* ws = (char*)d_ws;
  unsigned short* hA      = (unsigned short*)(ws);                  // 51.2 MB bf16
  unsigned*       colpack = (unsigned*)(ws + 51200000);             // 12.8 MB
  int*            row_ptr = (int*)(ws + 64000000);                  // 400 KB
  int*            cursor  = (int*)(ws + 64400128);                  // 400 KB
  int*            cnt8    = (int*)(ws + 64800256);                  // 3.2 MB
  int*            cnts    = (int*)(ws + 68000384);                  // 400 KB
  int*            bsum    = (int*)(ws + 68400512);                  // 2 KB
  int*            bofs    = (int*)(ws + 68402560);                  // 2 KB
  int*            cntT    = (int*)(ws + 68406656);                  // 26.7 KB
  int*            pofsT   = (int*)(ws + 68433536);                  // 26.7 KB
  unsigned short* wt0     = (unsigned short*)(ws + 68487296);       // 128 KB
  unsigned short* wt1     = (unsigned short*)(ws + 68618368);       // 128 KB
  // d_out (102.4 MB fp32) hosts bf16/scratch buffers until the final spmm:
  unsigned short* hB   = (unsigned short*)d_out;                    // [0, 51.2 MB)
  unsigned short* hC   = (unsigned short*)d_out + n_feat;           // [51.2, 102.4 MB)
  int2*           part = (int2*)((char*)d_out + 51200000);          // build-time only

  int Mb = (M + 255) / 256;                 // 391
  const int sblocks = 4 * ((M + 7) / 8);    // 4 slices x (8 nodes per block)
  const int gblocks = (M + 127) / 128;      // 782
  const int rpg = (M + 7) / 8;              // rows per XCD group
  unsigned gmagic = (unsigned)(((1ULL << 37) + rpg - 1) / (unsigned long long)rpg);

  // --- CSR build: ONE cooperative kernel (zero+count+sum+scan+apply+
  //     partition+scatter). part lives in d_out[51.2,76.8MB) until gemm. ---
  {
    void* args[] = {
      (void*)&rows, (void*)&cols, (void*)&vals,
      (void*)&cnt8, (void*)&cntT, (void*)&cnts,
      (void*)&bsum, (void*)&bofs, (void*)&pofsT,
      (void*)&row_ptr, (void*)&cursor,
      (void*)&part, (void*)&colpack,
      (void*)&W0, (void*)&W1, (void*)&wt0, (void*)&wt1,
      (void*)&n_edges, (void*)&gmagic, (void*)&M, (void*)&Mb
    };
    hipLaunchCooperativeKernel((const void*)coop_build, dim3(NBLK), dim3(256),
                               args, 0, stream);
  }

  // --- layer 0:  relu((0.5A)^2 (x @ W0))  [GEMM-first by associativity] ---
  gemm3<true ><<<gblocks, 256, 0, stream>>>(x,  wt0, hB, M);               // hB = x@W0
  spmm_slice<false, false><<<sblocks, 256, 0, stream>>>(hB, row_ptr, colpack, hA, M);
  spmm_slice<true,  false><<<sblocks, 256, 0, stream>>>(hA, row_ptr, colpack, hB, M);

  // --- layer 1:  (0.5A)^2 (h @ W1) ---
  gemm3<false><<<gblocks, 256, 0, stream>>>(hB, wt1, hC, M);               // hC = h@W1
  spmm_slice<false, false><<<sblocks, 256, 0, stream>>>(hC, row_ptr, colpack, hA, M);
  spmm_slice<false, true ><<<sblocks, 256, 0, stream>>>(hA, row_ptr, colpack, d_out, M);
}

// Round 13
// 1219.798 us; speedup vs baseline: 1.4615x; 1.4615x over previous
//
#include <hip/hip_runtime.h>
#include <hip/hip_bf16.h>
#include <hip/hip_fp16.h>

#define N_D 256
#define NBLK 832   // edge-pass grid; shared by count/partition/scatter2

typedef __attribute__((ext_vector_type(8))) short bf16x8;
typedef __attribute__((ext_vector_type(4))) float f32x4;

// f32 -> bf16 round-to-nearest-even (finite inputs)
__device__ __forceinline__ unsigned short f2bf(float f) {
  union { float f; unsigned u; } c; c.f = f;
  unsigned u = c.u;
  return (unsigned short)((u + 0x7fffu + ((u >> 16) & 1u)) >> 16);
}
__device__ __forceinline__ float asf(unsigned u) {
  union { unsigned u; float f; } c; c.u = u;
  return c.f;
}
__device__ __forceinline__ int grp_of(int r, unsigned gmagic) {
  int g = (int)(((unsigned long long)(unsigned)r * gmagic) >> 37);
  return min(g, 7);
}

// ---------- GEMM core: 128 rows/tile, 2 row-frags/wave x 16 col-frags --------
// Used by the standalone gemm3 kernel AND the fat1 fused dispatch.
template <bool AF32>
__device__ __forceinline__ void gemm_core(
    const void* __restrict__ H, const unsigned short* __restrict__ WT,
    unsigned short* __restrict__ C, int M, int bid) {
  const int wave = threadIdx.x >> 6;
  const int lane = threadIdx.x & 63;
  const int m = lane & 15;
  const int p = lane >> 4;
  const int row0 = bid * 128 + wave * 32;

  f32x4 acc0[16], acc1[16];
#pragma unroll
  for (int i = 0; i < 16; ++i) {
    acc0[i] = (f32x4){0.f, 0.f, 0.f, 0.f};
    acc1[i] = (f32x4){0.f, 0.f, 0.f, 0.f};
  }

  const int r0 = row0 + m;
  const int r1 = row0 + 16 + m;
  const bool ok0 = r0 < M, ok1 = r1 < M;

  for (int k0 = 0; k0 < N_D; k0 += 32) {
    bf16x8 a0 = {0,0,0,0,0,0,0,0}, a1 = {0,0,0,0,0,0,0,0};
    if (AF32) {
      if (ok0) {
        const float* ap = (const float*)H + (size_t)r0 * N_D + k0 + p * 8;
        const float4 f0 = *reinterpret_cast<const float4*>(ap);
        const float4 f1 = *reinterpret_cast<const float4*>(ap + 4);
        a0[0]=f2bf(f0.x); a0[1]=f2bf(f0.y); a0[2]=f2bf(f0.z); a0[3]=f2bf(f0.w);
        a0[4]=f2bf(f1.x); a0[5]=f2bf(f1.y); a0[6]=f2bf(f1.z); a0[7]=f2bf(f1.w);
      }
      if (ok1) {
        const float* ap = (const float*)H + (size_t)r1 * N_D + k0 + p * 8;
        const float4 f0 = *reinterpret_cast<const float4*>(ap);
        const float4 f1 = *reinterpret_cast<const float4*>(ap + 4);
        a1[0]=f2bf(f0.x); a1[1]=f2bf(f0.y); a1[2]=f2bf(f0.z); a1[3]=f2bf(f0.w);
        a1[4]=f2bf(f1.x); a1[5]=f2bf(f1.y); a1[6]=f2bf(f1.z); a1[7]=f2bf(f1.w);
      }
    } else {
      if (ok0) a0 = *reinterpret_cast<const bf16x8*>(
          (const unsigned short*)H + (size_t)r0 * N_D + k0 + p * 8);
      if (ok1) a1 = *reinterpret_cast<const bf16x8*>(
          (const unsigned short*)H + (size_t)r1 * N_D + k0 + p * 8);
    }
#pragma unroll
    for (int nt = 0; nt < 16; ++nt) {
      const bf16x8 b = *reinterpret_cast<const bf16x8*>(
          WT + (size_t)(nt * 16 + m) * N_D + k0 + p * 8);
      acc0[nt] = __builtin_amdgcn_mfma_f32_16x16x32_bf16(a0, b, acc0[nt], 0, 0, 0);
      acc1[nt] = __builtin_amdgcn_mfma_f32_16x16x32_bf16(a1, b, acc1[nt], 0, 0, 0);
    }
  }

  // C/D layout: col = lane&15 (=m), row = p*4 + rr within each 16x16 tile
#pragma unroll
  for (int nt = 0; nt < 16; ++nt) {
    const int col = nt * 16 + m;
#pragma unroll
    for (int rr = 0; rr < 4; ++rr) {
      const int ra = row0 + p * 4 + rr;
      const int rb = ra + 16;
      if (ra < M) C[(size_t)ra * N_D + col] = f2bf(acc0[nt][rr]);
      if (rb < M) C[(size_t)rb * N_D + col] = f2bf(acc1[nt][rr]);
    }
  }
}

// ---------- weight transpose: WT[n][k] = bf16(W[k][n]), both weights ---------
__global__ __launch_bounds__(256) void wconv_kernel(
    const float* __restrict__ W0, const float* __restrict__ W1,
    unsigned short* __restrict__ WT0, unsigned short* __restrict__ WT1) {
  const int w = blockIdx.x >> 8;
  const int k = blockIdx.x & 255;
  const int n = threadIdx.x;
  const float* W = w ? W1 : W0;
  unsigned short* WT = w ? WT1 : WT0;
  WT[(size_t)n * N_D + k] = f2bf(W[(size_t)k * N_D + n]);
}

// ---------- fat1: count histogram (blocks < NBLK) + gemm0 (blocks >= NBLK) ---
// count: cnt8[bid%8][r] XCD-local replicas (equal bid%8 -> same XCD).
// gemm0 (x@W0, fp32 A) is independent of the build -> overlaps count's
// atomic-bound blocks with MFMA-heavy blocks in ONE dispatch.
__global__ __launch_bounds__(256) void fat1_kernel(
    const int* __restrict__ rows, int* __restrict__ cnt8, int* __restrict__ cntT,
    int n_edges, unsigned gmagic, int M,
    const float* __restrict__ x, const unsigned short* __restrict__ WT0,
    unsigned short* __restrict__ hB) {
  if (blockIdx.x >= NBLK) {
    gemm_core<true>(x, WT0, hB, M, blockIdx.x - NBLK);
    return;
  }
  __shared__ int lcnt[8];
  if (threadIdx.x < 8) lcnt[threadIdx.x] = 0;
  __syncthreads();
  int* __restrict__ cnt = cnt8 + (size_t)(blockIdx.x & 7) * M;
  for (int e = blockIdx.x * 256 + threadIdx.x; e < n_edges; e += NBLK * 256) {
    const int r = rows[e];
    atomicAdd(&cnt[r], 1);
    atomicAdd(&lcnt[grp_of(r, gmagic)], 1);
  }
  __syncthreads();
  if (threadIdx.x < 8) cntT[threadIdx.x * NBLK + blockIdx.x] = lcnt[threadIdx.x];
}

// ---------- sum the 8 replicas; per-block totals for the hierarchical scan ----
__global__ __launch_bounds__(256) void sumcnt_kernel(
    const int* __restrict__ cnt8, int* __restrict__ cnts,
    int* __restrict__ bsum, int M) {
  __shared__ int wred[4];
  const int i = blockIdx.x * 256 + threadIdx.x;
  int s = 0;
  if (i < M) {
#pragma unroll
    for (int k = 0; k < 8; ++k) s += cnt8[(size_t)k * M + i];
    cnts[i] = s;
  }
  int t = s;
#pragma unroll
  for (int off = 32; off; off >>= 1) t += __shfl_down(t, off, 64);
  if ((threadIdx.x & 63) == 0) wred[threadIdx.x >> 6] = t;
  __syncthreads();
  if (threadIdx.x == 0) bsum[blockIdx.x] = wred[0] + wred[1] + wred[2] + wred[3];
}

// ---------- 256-thread exclusive scan (device fn); out[n] = total ----------
__device__ void scan256(const int* __restrict__ in, int* __restrict__ out, int n) {
  __shared__ int swsum[4];
  __shared__ int carry_sh;
  const int tid = threadIdx.x;
  const int lane = tid & 63;
  const int wid = tid >> 6;
  if (tid == 0) carry_sh = 0;
  __syncthreads();
  for (int base = 0; base < n; base += 1024) {
    const int i0 = base + tid * 4;
    int4 v = make_int4(0, 0, 0, 0);
    if (i0 + 3 < n) v = *reinterpret_cast<const int4*>(in + i0);
    else {
      if (i0     < n) v.x = in[i0];
      if (i0 + 1 < n) v.y = in[i0 + 1];
      if (i0 + 2 < n) v.z = in[i0 + 2];
    }
    const int s1 = v.x, s2 = s1 + v.y, s3 = s2 + v.z, s4 = s3 + v.w;
    int ws = s4;
#pragma unroll
    for (int off = 1; off < 64; off <<= 1) {
      int o = __shfl_up(ws, off, 64);
      if (lane >= off) ws += o;
    }
    if (lane == 63) swsum[wid] = ws;
    __syncthreads();
    if (wid == 0) {
      int t = (lane < 4) ? swsum[lane] : 0;
#pragma unroll
      for (int off = 1; off < 4; off <<= 1) {
        int o = __shfl_up(t, off, 64);
        if (lane >= off) t += o;
      }
      if (lane < 4) swsum[lane] = t;
    }
    __syncthreads();
    const int carry = carry_sh;
    const int tbase = carry + (wid ? swsum[wid - 1] : 0) + ws - s4;  // exclusive
    if (i0     < n) out[i0]     = tbase;
    if (i0 + 1 < n) out[i0 + 1] = tbase + s1;
    if (i0 + 2 < n) out[i0 + 2] = tbase + s2;
    if (i0 + 3 < n) out[i0 + 3] = tbase + s3;
    __syncthreads();
    if (tid == 0) carry_sh = carry + swsum[3];
    __syncthreads();
  }
  if (tid == 0) out[n] = carry_sh;
}

// ---------- both small scans in one launch ----------
__global__ __launch_bounds__(256) void scan2_kernel(
    const int* __restrict__ bsum, int* __restrict__ bofs, int Mb,
    const int* __restrict__ cntT, int* __restrict__ pofsT) {
  if (blockIdx.x == 0) scan256(bsum, bofs, Mb);
  else                 scan256(cntT, pofsT, 8 * NBLK);
}

// ---------- fat2: scan_apply (blocks < Mb) + partition (blocks >= Mb) --------
__global__ __launch_bounds__(256) void build2_kernel(
    const int* __restrict__ cnts, const int* __restrict__ bofs,
    int* __restrict__ row_ptr, int* __restrict__ cursor, int M, int Mb,
    const int* __restrict__ rows, const int* __restrict__ cols,
    const float* __restrict__ vals, const int* __restrict__ pofsT,
    int2* __restrict__ part, int n_edges, unsigned gmagic) {
  __shared__ int shmem[8];
  if (blockIdx.x < Mb) {
    const int tid = threadIdx.x;
    const int lane = tid & 63;
    const int wid = tid >> 6;
    const int i = blockIdx.x * 256 + tid;
    const int v = (i < M) ? cnts[i] : 0;
    int s = v;
#pragma unroll
    for (int off = 1; off < 64; off <<= 1) {
      int o = __shfl_up(s, off, 64);
      if (lane >= off) s += o;
    }
    if (lane == 63) shmem[wid] = s;
    __syncthreads();
    int add = 0;
    for (int k = 0; k < wid; ++k) add += shmem[k];
    const int excl = bofs[blockIdx.x] + add + s - v;
    if (i < M) { row_ptr[i] = excl; cursor[i] = excl; }
    if (i == M) row_ptr[M] = bofs[Mb];   // total edges
  } else {
    const int pb = blockIdx.x - Mb;      // 0..NBLK-1
    if (threadIdx.x < 8) shmem[threadIdx.x] = pofsT[threadIdx.x * NBLK + pb];
    __syncthreads();
    for (int e = pb * 256 + threadIdx.x; e < n_edges; e += NBLK * 256) {
      const int r = rows[e];
      const int g = grp_of(r, gmagic);
      const int slot = atomicAdd(&shmem[g], 1);
      const unsigned short hb = __half_as_ushort(__float2half_rn(vals[e] * 0.5f));
      int2 rv;
      rv.x = r;
      rv.y = (int)(((unsigned)cols[e] << 15) | ((unsigned)hb >> 1));
      part[slot] = rv;
    }
  }
}

// ---------- scatter within XCD-local group (write-merge friendly) ------------
__global__ __launch_bounds__(256) void scatter2_kernel(
    const int2* __restrict__ part, const int* __restrict__ pofsT,
    int* __restrict__ cursor, unsigned* __restrict__ colpack) {
  const int g  = blockIdx.x & 7;
  const int bk = blockIdx.x >> 3;
  const int nb = gridDim.x >> 3;
  const int s0 = pofsT[g * NBLK];
  const int s1 = pofsT[(g + 1) * NBLK];   // g=7 -> pofsT[8*NBLK] = total
  for (int i = s0 + bk * 256 + threadIdx.x; i < s1; i += nb * 256) {
    const int2 rv = part[i];
    const int pos = atomicAdd(&cursor[rv.x], 1);
    colpack[pos] = (unsigned)rv.y;
  }
}

// ---------- SpMM, feature-sliced (round-6 config: MLP 8, inline decode) ------
template <bool RELU, bool F32OUT>
__global__ __launch_bounds__(256) void spmm_slice(
    const unsigned short* __restrict__ hin, const int* __restrict__ row_ptr,
    const unsigned* __restrict__ colpack, void* __restrict__ hout,
    int n_nodes) {
  const int slice = blockIdx.x & 3;
  const int lane = threadIdx.x & 63;
  const int half = lane >> 5;
  const int sub  = lane & 31;
  const int wgid = ((blockIdx.x >> 2) * 256 + threadIdx.x) >> 6;  // node-pair id
  const int node = wgid * 2 + half;
  const bool ok = node < n_nodes;
  int start = 0, end = 0;
  if (ok) { start = row_ptr[node]; end = row_ptr[node + 1]; }

  const unsigned* __restrict__ hinw = reinterpret_cast<const unsigned*>(hin);
  const int fofs = slice * 32 + sub;       // uint index within a 128-uint row
  const int sbase = half << 5;

  float acc0 = 0.f, acc1 = 0.f;

  for (int base = start; base < end; base += 32) {
    const int cnt = min(32, end - base);
    unsigned u = 0;                        // u=0 -> (col=0, val=0) dummy
    if (base + sub < end) u = __builtin_nontemporal_load(&colpack[base + sub]);
    for (int t = 0; t < cnt; t += 8) {
      unsigned hv[8];
      float v[8];
#pragma unroll
      for (int j = 0; j < 8; ++j) {
        const unsigned ue = (unsigned)__shfl((int)u, sbase + t + j, 64);
        const int c = (int)(ue >> 15);
        v[j] = __half2float(__ushort_as_half((unsigned short)(ue << 1)));
        hv[j] = hinw[(size_t)c * 128 + fofs];   // 8 independent 4B gathers
      }
#pragma unroll
      for (int j = 0; j < 8; ++j) {
        acc0 += v[j] * asf(hv[j] << 16);
        acc1 += v[j] * asf(hv[j] & 0xffff0000u);
      }
    }
  }
  if (ok) {
    if (RELU) { acc0 = fmaxf(acc0, 0.f); acc1 = fmaxf(acc1, 0.f); }
    if (F32OUT) {
      reinterpret_cast<float2*>(hout)[(size_t)node * 128 + fofs] =
          make_float2(acc0, acc1);
    } else {
      reinterpret_cast<unsigned*>(hout)[(size_t)node * 128 + fofs] =
          (unsigned)f2bf(acc0) | ((unsigned)f2bf(acc1) << 16);
    }
  }
}

// ---------- standalone GEMM (layer 1) ----------
__global__ __launch_bounds__(256) void gemm3_bf16(
    const unsigned short* __restrict__ H, const unsigned short* __restrict__ WT,
    unsigned short* __restrict__ C, int M) {
  gemm_core<false>(H, WT, C, M, blockIdx.x);
}

extern "C" void kernel_launch(void* const* d_in, const int* in_sizes, int n_in,
                              void* d_out, int out_size, void* d_ws, size_t ws_size,
                              hipStream_t stream) {
  const float* x    = (const float*)d_in[0];
  const float* vals = (const float*)d_in[1];
  const float* W0   = (const float*)d_in[2];
  const float* W1   = (const float*)d_in[3];
  const int*   rows = (const int*)d_in[4];
  const int*   cols = (const int*)d_in[5];

  const int n_edges = in_sizes[1];
  const int M = in_sizes[0] / N_D;        // 100000
  const size_t n_feat = (size_t)M * N_D;  // 25.6M elements

  char* ws = (char*)d_ws;
  unsigned short* hA      = (unsigned short*)(ws);                  // 51.2 MB bf16
  unsigned*       colpack = (unsigned*)(ws + 51200000);             // 12.8 MB
  int*            row_ptr = (int*)(ws + 64000000);                  // 400 KB
  int*            cursor  = (int*)(ws + 64400128);                  // 400 KB
  int*            cnt8    = (int*)(ws + 64800256);                  // 3.2 MB
  int*            cnts    = (int*)(ws + 68000384);                  // 400 KB
  int*            bsum    = (int*)(ws + 68400512);                  // 2 KB
  int*            bofs    = (int*)(ws + 68402560);                  // 2 KB
  int*            cntT    = (int*)(ws + 68406656);                  // 26.7 KB
  int*            pofsT   = (int*)(ws + 68433536);                  // 26.7 KB
  unsigned short* wt0     = (unsigned short*)(ws + 68487296);       // 128 KB
  unsigned short* wt1     = (unsigned short*)(ws + 68618368);       // 128 KB
  // d_out (102.4 MB fp32) hosts bf16/scratch buffers until the final spmm:
  unsigned short* hB   = (unsigned short*)d_out;                    // [0, 51.2 MB)
  unsigned short* hC   = (unsigned short*)d_out + n_feat;           // [51.2, 102.4 MB)
  int2*           part = (int2*)((char*)d_out + 51200000);          // build-time only

  const int Mb = (M + 255) / 256;           // 391
  const int sblocks = 4 * ((M + 7) / 8);    // 4 slices x (8 nodes per block)
  const int gblocks = (M + 127) / 128;      // 782
  const int rpg = (M + 7) / 8;              // rows per XCD group
  const unsigned gmagic = (unsigned)(((1ULL << 37) + rpg - 1) / (unsigned long long)rpg);

  // --- build + layer-0 GEMM, overlapped ---
  hipMemsetAsync(cnt8, 0, (size_t)8 * M * sizeof(int), stream);
  wconv_kernel<<<512, 256, 0, stream>>>(W0, W1, wt0, wt1);
  // fat1: count (832 blocks) + gemm0 hB = x@W0 (782 blocks) in one dispatch
  fat1_kernel<<<NBLK + gblocks, 256, 0, stream>>>(rows, cnt8, cntT, n_edges,
                                                  gmagic, M, x, wt0, hB);
  sumcnt_kernel<<<Mb, 256, 0, stream>>>(cnt8, cnts, bsum, M);
  scan2_kernel<<<2, 256, 0, stream>>>(bsum, bofs, Mb, cntT, pofsT);
  build2_kernel<<<Mb + NBLK, 256, 0, stream>>>(cnts, bofs, row_ptr, cursor, M, Mb,
                                               rows, cols, vals, pofsT, part,
                                               n_edges, gmagic);
  scatter2_kernel<<<NBLK, 256, 0, stream>>>(part, pofsT, cursor, colpack);

  // --- layer 0:  relu((0.5A)^2 hB) ---
  spmm_slice<false, false><<<sblocks, 256, 0, stream>>>(hB, row_ptr, colpack, hA, M);
  spmm_slice<true,  false><<<sblocks, 256, 0, stream>>>(hA, row_ptr, colpack, hB, M);

  // --- layer 1:  (0.5A)^2 (h @ W1) ---
  gemm3_bf16<<<gblocks, 256, 0, stream>>>(hB, wt1, hC, M);
  spmm_slice<false, false><<<sblocks, 256, 0, stream>>>(hC, row_ptr, colpack, hA, M);
  spmm_slice<false, true ><<<sblocks, 256, 0, stream>>>(hA, row_ptr, colpack, d_out, M);
}

// Round 14
// 1124.861 us; speedup vs baseline: 1.5849x; 1.0844x over previous
//
#include <hip/hip_runtime.h>
#include <hip/hip_bf16.h>
#include <hip/hip_fp16.h>

#define N_D 256
#define NBLK 832      // partition grid; 8 chunks x 104 pblocks
#define CPB 104       // pblocks per chunk
#define RPG_MAX 12512 // max rows per XCD group (LDS histogram size)

typedef __attribute__((ext_vector_type(8))) short bf16x8;
typedef __attribute__((ext_vector_type(4))) float f32x4;

// f32 -> bf16 round-to-nearest-even (finite inputs)
__device__ __forceinline__ unsigned short f2bf(float f) {
  union { float f; unsigned u; } c; c.f = f;
  unsigned u = c.u;
  return (unsigned short)((u + 0x7fffu + ((u >> 16) & 1u)) >> 16);
}
__device__ __forceinline__ float asf(unsigned u) {
  union { unsigned u; float f; } c; c.u = u;
  return c.f;
}
__device__ __forceinline__ int grp_of(int r, unsigned gmagic) {
  int g = (int)(((unsigned long long)(unsigned)r * gmagic) >> 37);
  return min(g, 7);
}

// ---------- GEMM core: 128 rows/tile, 2 row-frags/wave x 16 col-frags --------
template <bool AF32>
__device__ __forceinline__ void gemm_core(
    const void* __restrict__ H, const unsigned short* __restrict__ WT,
    unsigned short* __restrict__ C, int M, int bid) {
  const int wave = threadIdx.x >> 6;
  const int lane = threadIdx.x & 63;
  const int m = lane & 15;
  const int p = lane >> 4;
  const int row0 = bid * 128 + wave * 32;

  f32x4 acc0[16], acc1[16];
#pragma unroll
  for (int i = 0; i < 16; ++i) {
    acc0[i] = (f32x4){0.f, 0.f, 0.f, 0.f};
    acc1[i] = (f32x4){0.f, 0.f, 0.f, 0.f};
  }

  const int r0 = row0 + m;
  const int r1 = row0 + 16 + m;
  const bool ok0 = r0 < M, ok1 = r1 < M;

  for (int k0 = 0; k0 < N_D; k0 += 32) {
    bf16x8 a0 = {0,0,0,0,0,0,0,0}, a1 = {0,0,0,0,0,0,0,0};
    if (AF32) {
      if (ok0) {
        const float* ap = (const float*)H + (size_t)r0 * N_D + k0 + p * 8;
        const float4 f0 = *reinterpret_cast<const float4*>(ap);
        const float4 f1 = *reinterpret_cast<const float4*>(ap + 4);
        a0[0]=f2bf(f0.x); a0[1]=f2bf(f0.y); a0[2]=f2bf(f0.z); a0[3]=f2bf(f0.w);
        a0[4]=f2bf(f1.x); a0[5]=f2bf(f1.y); a0[6]=f2bf(f1.z); a0[7]=f2bf(f1.w);
      }
      if (ok1) {
        const float* ap = (const float*)H + (size_t)r1 * N_D + k0 + p * 8;
        const float4 f0 = *reinterpret_cast<const float4*>(ap);
        const float4 f1 = *reinterpret_cast<const float4*>(ap + 4);
        a1[0]=f2bf(f0.x); a1[1]=f2bf(f0.y); a1[2]=f2bf(f0.z); a1[3]=f2bf(f0.w);
        a1[4]=f2bf(f1.x); a1[5]=f2bf(f1.y); a1[6]=f2bf(f1.z); a1[7]=f2bf(f1.w);
      }
    } else {
      if (ok0) a0 = *reinterpret_cast<const bf16x8*>(
          (const unsigned short*)H + (size_t)r0 * N_D + k0 + p * 8);
      if (ok1) a1 = *reinterpret_cast<const bf16x8*>(
          (const unsigned short*)H + (size_t)r1 * N_D + k0 + p * 8);
    }
#pragma unroll
    for (int nt = 0; nt < 16; ++nt) {
      const bf16x8 b = *reinterpret_cast<const bf16x8*>(
          WT + (size_t)(nt * 16 + m) * N_D + k0 + p * 8);
      acc0[nt] = __builtin_amdgcn_mfma_f32_16x16x32_bf16(a0, b, acc0[nt], 0, 0, 0);
      acc1[nt] = __builtin_amdgcn_mfma_f32_16x16x32_bf16(a1, b, acc1[nt], 0, 0, 0);
    }
  }

#pragma unroll
  for (int nt = 0; nt < 16; ++nt) {
    const int col = nt * 16 + m;
#pragma unroll
    for (int rr = 0; rr < 4; ++rr) {
      const int ra = row0 + p * 4 + rr;
      const int rb = ra + 16;
      if (ra < M) C[(size_t)ra * N_D + col] = f2bf(acc0[nt][rr]);
      if (rb < M) C[(size_t)rb * N_D + col] = f2bf(acc1[nt][rr]);
    }
  }
}

__global__ __launch_bounds__(256) void gemm3_f32(
    const float* __restrict__ H, const unsigned short* __restrict__ WT,
    unsigned short* __restrict__ C, int M) {
  gemm_core<true>(H, WT, C, M, blockIdx.x);
}
__global__ __launch_bounds__(256) void gemm3_bf16(
    const unsigned short* __restrict__ H, const unsigned short* __restrict__ WT,
    unsigned short* __restrict__ C, int M) {
  gemm_core<false>(H, WT, C, M, blockIdx.x);
}

// ---------- P0: per-(group,pblock) edge counts (LDS only) + weight transpose --
__global__ __launch_bounds__(256) void p0_kernel(
    const int* __restrict__ rows, int* __restrict__ cntT,
    int n_edges, unsigned gmagic,
    const float* __restrict__ W0, const float* __restrict__ W1,
    unsigned short* __restrict__ WT0, unsigned short* __restrict__ WT1) {
  if (blockIdx.x >= NBLK) {       // 512 trailing blocks: WT[n][k] = bf16(W[k][n])
    const int b = blockIdx.x - NBLK;
    const int w = b >> 8;
    const int k = b & 255;
    const int n = threadIdx.x;
    const float* W = w ? W1 : W0;
    unsigned short* WT = w ? WT1 : WT0;
    WT[(size_t)n * N_D + k] = f2bf(W[(size_t)k * N_D + n]);
    return;
  }
  __shared__ int l8[8];
  if (threadIdx.x < 8) l8[threadIdx.x] = 0;
  __syncthreads();
  for (int e = blockIdx.x * 256 + threadIdx.x; e < n_edges; e += NBLK * 256) {
    atomicAdd(&l8[grp_of(rows[e], gmagic)], 1);
  }
  __syncthreads();
  if (threadIdx.x < 8) cntT[threadIdx.x * NBLK + blockIdx.x] = l8[threadIdx.x];
}

// ---------- 256-thread exclusive scan; out[n] = total ----------
__global__ __launch_bounds__(256) void scan_one(
    const int* __restrict__ in, int* __restrict__ out, int n) {
  __shared__ int swsum[4];
  __shared__ int carry_sh;
  const int tid = threadIdx.x;
  const int lane = tid & 63;
  const int wid = tid >> 6;
  if (tid == 0) carry_sh = 0;
  __syncthreads();
  for (int base = 0; base < n; base += 1024) {
    const int i0 = base + tid * 4;
    int4 v = make_int4(0, 0, 0, 0);
    if (i0 + 3 < n) v = *reinterpret_cast<const int4*>(in + i0);
    else {
      if (i0     < n) v.x = in[i0];
      if (i0 + 1 < n) v.y = in[i0 + 1];
      if (i0 + 2 < n) v.z = in[i0 + 2];
    }
    const int s1 = v.x, s2 = s1 + v.y, s3 = s2 + v.z, s4 = s3 + v.w;
    int ws = s4;
#pragma unroll
    for (int off = 1; off < 64; off <<= 1) {
      int o = __shfl_up(ws, off, 64);
      if (lane >= off) ws += o;
    }
    if (lane == 63) swsum[wid] = ws;
    __syncthreads();
    if (wid == 0) {
      int t = (lane < 4) ? swsum[lane] : 0;
#pragma unroll
      for (int off = 1; off < 4; off <<= 1) {
        int o = __shfl_up(t, off, 64);
        if (lane >= off) t += o;
      }
      if (lane < 4) swsum[lane] = t;
    }
    __syncthreads();
    const int carry = carry_sh;
    const int tbase = carry + (wid ? swsum[wid - 1] : 0) + ws - s4;  // exclusive
    if (i0     < n) out[i0]     = tbase;
    if (i0 + 1 < n) out[i0 + 1] = tbase + s1;
    if (i0 + 2 < n) out[i0 + 2] = tbase + s2;
    if (i0 + 3 < n) out[i0 + 3] = tbase + s3;
    __syncthreads();
    if (tid == 0) carry_sh = carry + swsum[3];
    __syncthreads();
  }
  if (tid == 0) out[n] = carry_sh;
}

// ---------- P1: partition edges into [group][pblock]-contiguous segments -----
__global__ __launch_bounds__(256) void partition_kernel(
    const int* __restrict__ rows, const int* __restrict__ cols,
    const float* __restrict__ vals, const int* __restrict__ pofsT,
    int2* __restrict__ part, int n_edges, unsigned gmagic) {
  __shared__ int lofs[8];
  if (threadIdx.x < 8) lofs[threadIdx.x] = pofsT[threadIdx.x * NBLK + blockIdx.x];
  __syncthreads();
  for (int e = blockIdx.x * 256 + threadIdx.x; e < n_edges; e += NBLK * 256) {
    const int r = rows[e];
    const int g = grp_of(r, gmagic);
    const int slot = atomicAdd(&lofs[g], 1);
    const unsigned short hb = __half_as_ushort(__float2half_rn(vals[e] * 0.5f));
    int2 rv;
    rv.x = r;
    rv.y = (int)(((unsigned)cols[e] << 15) | ((unsigned)hb >> 1));
    part[slot] = rv;
  }
}

// ---------- P2: per-(group,chunk) row histogram in LDS -> cntc (NO atomics) --
// 64 blocks; g = bid&7 (same-XCD per group), b = bid>>3 (chunk of 104 pblocks).
__global__ __launch_bounds__(256) void hist_kernel(
    const int2* __restrict__ part, const int* __restrict__ pofsT,
    int* __restrict__ cntc, int M, int rpg) {
  const int g = blockIdx.x & 7;
  const int b = blockIdx.x >> 3;
  const int r0 = g * rpg;
  const int nr = min(rpg, M - r0);
  __shared__ int lh[RPG_MAX];
  for (int r = threadIdx.x; r < nr; r += 256) lh[r] = 0;
  __syncthreads();
  const int s0 = pofsT[g * NBLK + b * CPB];
  const int s1 = pofsT[g * NBLK + (b + 1) * CPB];
  for (int i = s0 + threadIdx.x; i < s1; i += 256) {
    atomicAdd(&lh[part[i].x - r0], 1);   // LDS atomic, random over 12.5K
  }
  __syncthreads();
  int* dst = cntc + (size_t)(g * 8 + b) * rpg;
  for (int r = threadIdx.x; r < nr; r += 256) dst[r] = lh[r];  // coalesced
}

// ---------- P3a: cnts[r] = sum over chunks; cntc -> exclusive chunk prefix ---
__global__ __launch_bounds__(256) void sumcnt2_kernel(
    int* __restrict__ cntc, int* __restrict__ cnts,
    int* __restrict__ bsum, int M, int rpg) {
  __shared__ int wred[4];
  const int i = blockIdx.x * 256 + threadIdx.x;
  int s = 0;
  if (i < M) {
    const int g = i / rpg;
    const int rr = i - g * rpg;
    int* base = cntc + (size_t)g * 8 * rpg + rr;
#pragma unroll
    for (int b = 0; b < 8; ++b) {
      const int c = base[(size_t)b * rpg];
      base[(size_t)b * rpg] = s;          // exclusive prefix along chunks
      s += c;
    }
    cnts[i] = s;
  }
  int t = s;
#pragma unroll
  for (int off = 32; off; off >>= 1) t += __shfl_down(t, off, 64);
  if ((threadIdx.x & 63) == 0) wred[threadIdx.x >> 6] = t;
  __syncthreads();
  if (threadIdx.x == 0) bsum[blockIdx.x] = wred[0] + wred[1] + wred[2] + wred[3];
}

// ---------- P3c: row_ptr = bofs[chunk] + intra-chunk exclusive scan ----------
__global__ __launch_bounds__(256) void apply_kernel(
    const int* __restrict__ cnts, const int* __restrict__ bofs,
    int* __restrict__ row_ptr, int M) {
  __shared__ int wsum[4];
  const int tid = threadIdx.x;
  const int lane = tid & 63;
  const int wid = tid >> 6;
  const int i = blockIdx.x * 256 + tid;
  const int v = (i < M) ? cnts[i] : 0;
  int s = v;
#pragma unroll
  for (int off = 1; off < 64; off <<= 1) {
    int o = __shfl_up(s, off, 64);
    if (lane >= off) s += o;
  }
  if (lane == 63) wsum[wid] = s;
  __syncthreads();
  int add = 0;
  for (int k = 0; k < wid; ++k) add += wsum[k];
  const int excl = bofs[blockIdx.x] + add + s - v;
  if (i < M) row_ptr[i] = excl;
  if (i == M) row_ptr[M] = bofs[gridDim.x];
}

// ---------- P4: scatter via LDS cursors (NO global atomics) ----------
__global__ __launch_bounds__(256) void scatter3_kernel(
    const int2* __restrict__ part, const int* __restrict__ pofsT,
    const int* __restrict__ row_ptr, const int* __restrict__ cntc,
    unsigned* __restrict__ colpack, int M, int rpg) {
  const int g = blockIdx.x & 7;
  const int b = blockIdx.x >> 3;
  const int r0 = g * rpg;
  const int nr = min(rpg, M - r0);
  __shared__ int lc[RPG_MAX];
  const int* pfx = cntc + (size_t)(g * 8 + b) * rpg;
  for (int r = threadIdx.x; r < nr; r += 256)
    lc[r] = row_ptr[r0 + r] + pfx[r];
  __syncthreads();
  const int s0 = pofsT[g * NBLK + b * CPB];
  const int s1 = pofsT[g * NBLK + (b + 1) * CPB];
  for (int i = s0 + threadIdx.x; i < s1; i += 256) {
    const int2 rv = part[i];
    const int pos = atomicAdd(&lc[rv.x - r0], 1);   // LDS atomic
    colpack[pos] = (unsigned)rv.y;                  // XCD-local, L2-merged
  }
}

// ---------- SpMM, feature-sliced (round-6 config: MLP 8, inline decode) ------
template <bool RELU, bool F32OUT>
__global__ __launch_bounds__(256) void spmm_slice(
    const unsigned short* __restrict__ hin, const int* __restrict__ row_ptr,
    const unsigned* __restrict__ colpack, void* __restrict__ hout,
    int n_nodes) {
  const int slice = blockIdx.x & 3;
  const int lane = threadIdx.x & 63;
  const int half = lane >> 5;
  const int sub  = lane & 31;
  const int wgid = ((blockIdx.x >> 2) * 256 + threadIdx.x) >> 6;  // node-pair id
  const int node = wgid * 2 + half;
  const bool ok = node < n_nodes;
  int start = 0, end = 0;
  if (ok) { start = row_ptr[node]; end = row_ptr[node + 1]; }

  const unsigned* __restrict__ hinw = reinterpret_cast<const unsigned*>(hin);
  const int fofs = slice * 32 + sub;       // uint index within a 128-uint row
  const int sbase = half << 5;

  float acc0 = 0.f, acc1 = 0.f;

  for (int base = start; base < end; base += 32) {
    const int cnt = min(32, end - base);
    unsigned u = 0;                        // u=0 -> (col=0, val=0) dummy
    if (base + sub < end) u = __builtin_nontemporal_load(&colpack[base + sub]);
    for (int t = 0; t < cnt; t += 8) {
      unsigned hv[8];
      float v[8];
#pragma unroll
      for (int j = 0; j < 8; ++j) {
        const unsigned ue = (unsigned)__shfl((int)u, sbase + t + j, 64);
        const int c = (int)(ue >> 15);
        v[j] = __half2float(__ushort_as_half((unsigned short)(ue << 1)));
        hv[j] = hinw[(size_t)c * 128 + fofs];   // 8 independent 4B gathers
      }
#pragma unroll
      for (int j = 0; j < 8; ++j) {
        acc0 += v[j] * asf(hv[j] << 16);
        acc1 += v[j] * asf(hv[j] & 0xffff0000u);
      }
    }
  }
  if (ok) {
    if (RELU) { acc0 = fmaxf(acc0, 0.f); acc1 = fmaxf(acc1, 0.f); }
    if (F32OUT) {
      reinterpret_cast<float2*>(hout)[(size_t)node * 128 + fofs] =
          make_float2(acc0, acc1);
    } else {
      reinterpret_cast<unsigned*>(hout)[(size_t)node * 128 + fofs] =
          (unsigned)f2bf(acc0) | ((unsigned)f2bf(acc1) << 16);
    }
  }
}

extern "C" void kernel_launch(void* const* d_in, const int* in_sizes, int n_in,
                              void* d_out, int out_size, void* d_ws, size_t ws_size,
                              hipStream_t stream) {
  const float* x    = (const float*)d_in[0];
  const float* vals = (const float*)d_in[1];
  const float* W0   = (const float*)d_in[2];
  const float* W1   = (const float*)d_in[3];
  const int*   rows = (const int*)d_in[4];
  const int*   cols = (const int*)d_in[5];

  const int n_edges = in_sizes[1];
  const int M = in_sizes[0] / N_D;        // 100000
  const size_t n_feat = (size_t)M * N_D;  // 25.6M elements

  char* ws = (char*)d_ws;
  unsigned short* hA      = (unsigned short*)(ws);                  // 51.2 MB bf16
  unsigned*       colpack = (unsigned*)(ws + 51200000);             // 12.8 MB
  int*            row_ptr = (int*)(ws + 64000000);                  // 400 KB
  int*            cnts    = (int*)(ws + 64400128);                  // 400 KB
  int*            cntc    = (int*)(ws + 64800256);                  // 3.2 MB (64*rpg)
  int*            bsum    = (int*)(ws + 68000384);                  // 2 KB
  int*            bofs    = (int*)(ws + 68002944);                  // 2 KB
  int*            cntT    = (int*)(ws + 68005504);                  // 26.7 KB
  int*            pofsT   = (int*)(ws + 68033536);                  // 26.7 KB
  unsigned short* wt0     = (unsigned short*)(ws + 68061568);       // 128 KB
  unsigned short* wt1     = (unsigned short*)(ws + 68192640);       // 128 KB
  // d_out (102.4 MB fp32) hosts bf16/scratch buffers until the final spmm:
  unsigned short* hB   = (unsigned short*)d_out;                    // [0, 51.2 MB)
  unsigned short* hC   = (unsigned short*)d_out + n_feat;           // [51.2, 102.4 MB)
  int2*           part = (int2*)((char*)d_out + 51200000);          // build-time only

  const int Mb = (M + 255) / 256;           // 391
  const int sblocks = 4 * ((M + 7) / 8);    // 4 slices x (8 nodes per block)
  const int gblocks = (M + 127) / 128;      // 782
  const int rpg = (M + 7) / 8;              // 12500 rows per XCD group
  const unsigned gmagic = (unsigned)(((1ULL << 37) + rpg - 1) / (unsigned long long)rpg);

  // --- atomic-free CSR build ---
  p0_kernel<<<NBLK + 512, 256, 0, stream>>>(rows, cntT, n_edges, gmagic,
                                            W0, W1, wt0, wt1);
  scan_one<<<1, 256, 0, stream>>>(cntT, pofsT, 8 * NBLK);
  gemm3_f32<<<gblocks, 256, 0, stream>>>(x, wt0, hB, M);   // hB = x@W0 (indep of build)
  partition_kernel<<<NBLK, 256, 0, stream>>>(rows, cols, vals, pofsT, part,
                                             n_edges, gmagic);
  hist_kernel<<<64, 256, 0, stream>>>(part, pofsT, cntc, M, rpg);
  sumcnt2_kernel<<<Mb, 256, 0, stream>>>(cntc, cnts, bsum, M, rpg);
  scan_one<<<1, 256, 0, stream>>>(bsum, bofs, Mb);
  apply_kernel<<<Mb, 256, 0, stream>>>(cnts, bofs, row_ptr, M);
  scatter3_kernel<<<64, 256, 0, stream>>>(part, pofsT, row_ptr, cntc,
                                          colpack, M, rpg);

  // --- layer 0:  relu((0.5A)^2 hB)  [GEMM-first by associativity] ---
  spmm_slice<false, false><<<sblocks, 256, 0, stream>>>(hB, row_ptr, colpack, hA, M);
  spmm_slice<true,  false><<<sblocks, 256, 0, stream>>>(hA, row_ptr, colpack, hB, M);

  // --- layer 1:  (0.5A)^2 (h @ W1) ---
  gemm3_bf16<<<gblocks, 256, 0, stream>>>(hB, wt1, hC, M);
  spmm_slice<false, false><<<sblocks, 256, 0, stream>>>(hC, row_ptr, colpack, hA, M);
  spmm_slice<false, true ><<<sblocks, 256, 0, stream>>>(hA, row_ptr, colpack, d_out, M);
}

// Round 15
// 1076.516 us; speedup vs baseline: 1.6560x; 1.0449x over previous
//
#include <hip/hip_runtime.h>
#include <hip/hip_bf16.h>
#include <hip/hip_fp16.h>

#define N_D 256
#define NBLK 832      // partition grid; 16 chunks x 52 pblocks per group
#define CPB 52        // pblocks per chunk
#define NCH 16        // chunks per group
#define RPG_MAX 12512 // max rows per XCD group (LDS histogram size)

typedef __attribute__((ext_vector_type(8))) short bf16x8;
typedef __attribute__((ext_vector_type(4))) float f32x4;

// f32 -> bf16 round-to-nearest-even (finite inputs)
__device__ __forceinline__ unsigned short f2bf(float f) {
  union { float f; unsigned u; } c; c.f = f;
  unsigned u = c.u;
  return (unsigned short)((u + 0x7fffu + ((u >> 16) & 1u)) >> 16);
}
__device__ __forceinline__ float asf(unsigned u) {
  union { unsigned u; float f; } c; c.u = u;
  return c.f;
}
__device__ __forceinline__ int grp_of(int r, unsigned gmagic) {
  int g = (int)(((unsigned long long)(unsigned)r * gmagic) >> 37);
  return min(g, 7);
}

// ---------- GEMM core: 128 rows/tile, 2 row-frags/wave x 16 col-frags --------
template <bool AF32>
__device__ __forceinline__ void gemm_core(
    const void* __restrict__ H, const unsigned short* __restrict__ WT,
    unsigned short* __restrict__ C, int M, int bid) {
  const int wave = threadIdx.x >> 6;
  const int lane = threadIdx.x & 63;
  const int m = lane & 15;
  const int p = lane >> 4;
  const int row0 = bid * 128 + wave * 32;

  f32x4 acc0[16], acc1[16];
#pragma unroll
  for (int i = 0; i < 16; ++i) {
    acc0[i] = (f32x4){0.f, 0.f, 0.f, 0.f};
    acc1[i] = (f32x4){0.f, 0.f, 0.f, 0.f};
  }

  const int r0 = row0 + m;
  const int r1 = row0 + 16 + m;
  const bool ok0 = r0 < M, ok1 = r1 < M;

  for (int k0 = 0; k0 < N_D; k0 += 32) {
    bf16x8 a0 = {0,0,0,0,0,0,0,0}, a1 = {0,0,0,0,0,0,0,0};
    if (AF32) {
      if (ok0) {
        const float* ap = (const float*)H + (size_t)r0 * N_D + k0 + p * 8;
        const float4 f0 = *reinterpret_cast<const float4*>(ap);
        const float4 f1 = *reinterpret_cast<const float4*>(ap + 4);
        a0[0]=f2bf(f0.x); a0[1]=f2bf(f0.y); a0[2]=f2bf(f0.z); a0[3]=f2bf(f0.w);
        a0[4]=f2bf(f1.x); a0[5]=f2bf(f1.y); a0[6]=f2bf(f1.z); a0[7]=f2bf(f1.w);
      }
      if (ok1) {
        const float* ap = (const float*)H + (size_t)r1 * N_D + k0 + p * 8;
        const float4 f0 = *reinterpret_cast<const float4*>(ap);
        const float4 f1 = *reinterpret_cast<const float4*>(ap + 4);
        a1[0]=f2bf(f0.x); a1[1]=f2bf(f0.y); a1[2]=f2bf(f0.z); a1[3]=f2bf(f0.w);
        a1[4]=f2bf(f1.x); a1[5]=f2bf(f1.y); a1[6]=f2bf(f1.z); a1[7]=f2bf(f1.w);
      }
    } else {
      if (ok0) a0 = *reinterpret_cast<const bf16x8*>(
          (const unsigned short*)H + (size_t)r0 * N_D + k0 + p * 8);
      if (ok1) a1 = *reinterpret_cast<const bf16x8*>(
          (const unsigned short*)H + (size_t)r1 * N_D + k0 + p * 8);
    }
#pragma unroll
    for (int nt = 0; nt < 16; ++nt) {
      const bf16x8 b = *reinterpret_cast<const bf16x8*>(
          WT + (size_t)(nt * 16 + m) * N_D + k0 + p * 8);
      acc0[nt] = __builtin_amdgcn_mfma_f32_16x16x32_bf16(a0, b, acc0[nt], 0, 0, 0);
      acc1[nt] = __builtin_amdgcn_mfma_f32_16x16x32_bf16(a1, b, acc1[nt], 0, 0, 0);
    }
  }

#pragma unroll
  for (int nt = 0; nt < 16; ++nt) {
    const int col = nt * 16 + m;
#pragma unroll
    for (int rr = 0; rr < 4; ++rr) {
      const int ra = row0 + p * 4 + rr;
      const int rb = ra + 16;
      if (ra < M) C[(size_t)ra * N_D + col] = f2bf(acc0[nt][rr]);
      if (rb < M) C[(size_t)rb * N_D + col] = f2bf(acc1[nt][rr]);
    }
  }
}

__global__ __launch_bounds__(256) void gemm3_bf16(
    const unsigned short* __restrict__ H, const unsigned short* __restrict__ WT,
    unsigned short* __restrict__ C, int M) {
  gemm_core<false>(H, WT, C, M, blockIdx.x);
}

// ---------- P0: per-(group,pblock) edge counts (LDS only) + weight transpose --
__global__ __launch_bounds__(256) void p0_kernel(
    const int* __restrict__ rows, int* __restrict__ cntT,
    int n_edges, unsigned gmagic,
    const float* __restrict__ W0, const float* __restrict__ W1,
    unsigned short* __restrict__ WT0, unsigned short* __restrict__ WT1) {
  if (blockIdx.x >= NBLK) {       // 512 trailing blocks: WT[n][k] = bf16(W[k][n])
    const int b = blockIdx.x - NBLK;
    const int w = b >> 8;
    const int k = b & 255;
    const int n = threadIdx.x;
    const float* W = w ? W1 : W0;
    unsigned short* WT = w ? WT1 : WT0;
    WT[(size_t)n * N_D + k] = f2bf(W[(size_t)k * N_D + n]);
    return;
  }
  __shared__ int l8[8];
  if (threadIdx.x < 8) l8[threadIdx.x] = 0;
  __syncthreads();
  for (int e = blockIdx.x * 256 + threadIdx.x; e < n_edges; e += NBLK * 256) {
    atomicAdd(&l8[grp_of(rows[e], gmagic)], 1);
  }
  __syncthreads();
  if (threadIdx.x < 8) cntT[threadIdx.x * NBLK + blockIdx.x] = l8[threadIdx.x];
}

// ---------- 256-thread exclusive scan; out[n] = total ----------
__global__ __launch_bounds__(256) void scan_one(
    const int* __restrict__ in, int* __restrict__ out, int n) {
  __shared__ int swsum[4];
  __shared__ int carry_sh;
  const int tid = threadIdx.x;
  const int lane = tid & 63;
  const int wid = tid >> 6;
  if (tid == 0) carry_sh = 0;
  __syncthreads();
  for (int base = 0; base < n; base += 1024) {
    const int i0 = base + tid * 4;
    int4 v = make_int4(0, 0, 0, 0);
    if (i0 + 3 < n) v = *reinterpret_cast<const int4*>(in + i0);
    else {
      if (i0     < n) v.x = in[i0];
      if (i0 + 1 < n) v.y = in[i0 + 1];
      if (i0 + 2 < n) v.z = in[i0 + 2];
    }
    const int s1 = v.x, s2 = s1 + v.y, s3 = s2 + v.z, s4 = s3 + v.w;
    int ws = s4;
#pragma unroll
    for (int off = 1; off < 64; off <<= 1) {
      int o = __shfl_up(ws, off, 64);
      if (lane >= off) ws += o;
    }
    if (lane == 63) swsum[wid] = ws;
    __syncthreads();
    if (wid == 0) {
      int t = (lane < 4) ? swsum[lane] : 0;
#pragma unroll
      for (int off = 1; off < 4; off <<= 1) {
        int o = __shfl_up(t, off, 64);
        if (lane >= off) t += o;
      }
      if (lane < 4) swsum[lane] = t;
    }
    __syncthreads();
    const int carry = carry_sh;
    const int tbase = carry + (wid ? swsum[wid - 1] : 0) + ws - s4;  // exclusive
    if (i0     < n) out[i0]     = tbase;
    if (i0 + 1 < n) out[i0 + 1] = tbase + s1;
    if (i0 + 2 < n) out[i0 + 2] = tbase + s2;
    if (i0 + 3 < n) out[i0 + 3] = tbase + s3;
    __syncthreads();
    if (tid == 0) carry_sh = carry + swsum[3];
    __syncthreads();
  }
  if (tid == 0) out[n] = carry_sh;
}

// ---------- fatpg: partition (blocks < NBLK) + gemm0 (blocks >= NBLK) --------
// partition and gemm0 (x@W0) are independent -> overlap in one dispatch
// (max-not-sum, r13-verified). gemm blocks fill CUs while partition drains.
__global__ __launch_bounds__(256) void fatpg_kernel(
    const int* __restrict__ rows, const int* __restrict__ cols,
    const float* __restrict__ vals, const int* __restrict__ pofsT,
    int2* __restrict__ part, int n_edges, unsigned gmagic,
    const float* __restrict__ x, const unsigned short* __restrict__ WT0,
    unsigned short* __restrict__ hB, int M) {
  if (blockIdx.x >= NBLK) {
    gemm_core<true>(x, WT0, hB, M, blockIdx.x - NBLK);
    return;
  }
  __shared__ int lofs[8];
  if (threadIdx.x < 8) lofs[threadIdx.x] = pofsT[threadIdx.x * NBLK + blockIdx.x];
  __syncthreads();
  for (int e = blockIdx.x * 256 + threadIdx.x; e < n_edges; e += NBLK * 256) {
    const int r = rows[e];
    const int g = grp_of(r, gmagic);
    const int slot = atomicAdd(&lofs[g], 1);
    const unsigned short hb = __half_as_ushort(__float2half_rn(vals[e] * 0.5f));
    int2 rv;
    rv.x = r;
    rv.y = (int)(((unsigned)cols[e] << 15) | ((unsigned)hb >> 1));
    part[slot] = rv;
  }
}

// ---------- P2: per-(group,chunk) row histogram in LDS -> cntc (NO atomics) --
// 128 blocks; g = bid&7 (same-XCD per group), b = bid>>3 (chunk of 52 pblocks).
__global__ __launch_bounds__(256) void hist_kernel(
    const int2* __restrict__ part, const int* __restrict__ pofsT,
    int* __restrict__ cntc, int M, int rpg) {
  const int g = blockIdx.x & 7;
  const int b = blockIdx.x >> 3;
  const int r0 = g * rpg;
  const int nr = min(rpg, M - r0);
  __shared__ int lh[RPG_MAX];
  for (int r = threadIdx.x; r < nr; r += 256) lh[r] = 0;
  __syncthreads();
  const int s0 = pofsT[g * NBLK + b * CPB];
  const int s1 = pofsT[g * NBLK + (b + 1) * CPB];
  for (int i = s0 + threadIdx.x; i < s1; i += 256) {
    atomicAdd(&lh[part[i].x - r0], 1);   // LDS atomic, random over 12.5K
  }
  __syncthreads();
  int* dst = cntc + (size_t)(g * NCH + b) * rpg;
  for (int r = threadIdx.x; r < nr; r += 256) dst[r] = lh[r];  // coalesced
}

// ---------- P3a: cnts[r] = sum over chunks; cntc -> exclusive chunk prefix ---
__global__ __launch_bounds__(256) void sumcnt2_kernel(
    int* __restrict__ cntc, int* __restrict__ cnts,
    int* __restrict__ bsum, int M, int rpg) {
  __shared__ int wred[4];
  const int i = blockIdx.x * 256 + threadIdx.x;
  int s = 0;
  if (i < M) {
    const int g = i / rpg;
    const int rr = i - g * rpg;
    int* base = cntc + (size_t)g * NCH * rpg + rr;
#pragma unroll
    for (int b = 0; b < NCH; ++b) {
      const int c = base[(size_t)b * rpg];
      base[(size_t)b * rpg] = s;          // exclusive prefix along chunks
      s += c;
    }
    cnts[i] = s;
  }
  int t = s;
#pragma unroll
  for (int off = 32; off; off >>= 1) t += __shfl_down(t, off, 64);
  if ((threadIdx.x & 63) == 0) wred[threadIdx.x >> 6] = t;
  __syncthreads();
  if (threadIdx.x == 0) bsum[blockIdx.x] = wred[0] + wred[1] + wred[2] + wred[3];
}

// ---------- P3c: row_ptr = bofs[chunk] + intra-chunk exclusive scan ----------
__global__ __launch_bounds__(256) void apply_kernel(
    const int* __restrict__ cnts, const int* __restrict__ bofs,
    int* __restrict__ row_ptr, int M) {
  __shared__ int wsum[4];
  const int tid = threadIdx.x;
  const int lane = tid & 63;
  const int wid = tid >> 6;
  const int i = blockIdx.x * 256 + tid;
  const int v = (i < M) ? cnts[i] : 0;
  int s = v;
#pragma unroll
  for (int off = 1; off < 64; off <<= 1) {
    int o = __shfl_up(s, off, 64);
    if (lane >= off) s += o;
  }
  if (lane == 63) wsum[wid] = s;
  __syncthreads();
  int add = 0;
  for (int k = 0; k < wid; ++k) add += wsum[k];
  const int excl = bofs[blockIdx.x] + add + s - v;
  if (i < M) row_ptr[i] = excl;
  if (i == M) row_ptr[M] = bofs[gridDim.x];
}

// ---------- P4: scatter via LDS cursors (NO global atomics) ----------
__global__ __launch_bounds__(256) void scatter3_kernel(
    const int2* __restrict__ part, const int* __restrict__ pofsT,
    const int* __restrict__ row_ptr, const int* __restrict__ cntc,
    unsigned* __restrict__ colpack, int M, int rpg) {
  const int g = blockIdx.x & 7;
  const int b = blockIdx.x >> 3;
  const int r0 = g * rpg;
  const int nr = min(rpg, M - r0);
  __shared__ int lc[RPG_MAX];
  const int* pfx = cntc + (size_t)(g * NCH + b) * rpg;
  for (int r = threadIdx.x; r < nr; r += 256)
    lc[r] = row_ptr[r0 + r] + pfx[r];
  __syncthreads();
  const int s0 = pofsT[g * NBLK + b * CPB];
  const int s1 = pofsT[g * NBLK + (b + 1) * CPB];
  for (int i = s0 + threadIdx.x; i < s1; i += 256) {
    const int2 rv = part[i];
    const int pos = atomicAdd(&lc[rv.x - r0], 1);   // LDS atomic
    colpack[pos] = (unsigned)rv.y;                  // XCD-local, L2-merged
  }
}

// ---------- SpMM, feature-sliced (round-6 config: MLP 8, inline decode) ------
template <bool RELU, bool F32OUT>
__global__ __launch_bounds__(256) void spmm_slice(
    const unsigned short* __restrict__ hin, const int* __restrict__ row_ptr,
    const unsigned* __restrict__ colpack, void* __restrict__ hout,
    int n_nodes) {
  const int slice = blockIdx.x & 3;
  const int lane = threadIdx.x & 63;
  const int half = lane >> 5;
  const int sub  = lane & 31;
  const int wgid = ((blockIdx.x >> 2) * 256 + threadIdx.x) >> 6;  // node-pair id
  const int node = wgid * 2 + half;
  const bool ok = node < n_nodes;
  int start = 0, end = 0;
  if (ok) { start = row_ptr[node]; end = row_ptr[node + 1]; }

  const unsigned* __restrict__ hinw = reinterpret_cast<const unsigned*>(hin);
  const int fofs = slice * 32 + sub;       // uint index within a 128-uint row
  const int sbase = half << 5;

  float acc0 = 0.f, acc1 = 0.f;

  for (int base = start; base < end; base += 32) {
    const int cnt = min(32, end - base);
    unsigned u = 0;                        // u=0 -> (col=0, val=0) dummy
    if (base + sub < end) u = __builtin_nontemporal_load(&colpack[base + sub]);
    for (int t = 0; t < cnt; t += 8) {
      unsigned hv[8];
      float v[8];
#pragma unroll
      for (int j = 0; j < 8; ++j) {
        const unsigned ue = (unsigned)__shfl((int)u, sbase + t + j, 64);
        const int c = (int)(ue >> 15);
        v[j] = __half2float(__ushort_as_half((unsigned short)(ue << 1)));
        hv[j] = hinw[(size_t)c * 128 + fofs];   // 8 independent 4B gathers
      }
#pragma unroll
      for (int j = 0; j < 8; ++j) {
        acc0 += v[j] * asf(hv[j] << 16);
        acc1 += v[j] * asf(hv[j] & 0xffff0000u);
      }
    }
  }
  if (ok) {
    if (RELU) { acc0 = fmaxf(acc0, 0.f); acc1 = fmaxf(acc1, 0.f); }
    if (F32OUT) {
      reinterpret_cast<float2*>(hout)[(size_t)node * 128 + fofs] =
          make_float2(acc0, acc1);
    } else {
      reinterpret_cast<unsigned*>(hout)[(size_t)node * 128 + fofs] =
          (unsigned)f2bf(acc0) | ((unsigned)f2bf(acc1) << 16);
    }
  }
}

extern "C" void kernel_launch(void* const* d_in, const int* in_sizes, int n_in,
                              void* d_out, int out_size, void* d_ws, size_t ws_size,
                              hipStream_t stream) {
  const float* x    = (const float*)d_in[0];
  const float* vals = (const float*)d_in[1];
  const float* W0   = (const float*)d_in[2];
  const float* W1   = (const float*)d_in[3];
  const int*   rows = (const int*)d_in[4];
  const int*   cols = (const int*)d_in[5];

  const int n_edges = in_sizes[1];
  const int M = in_sizes[0] / N_D;        // 100000
  const size_t n_feat = (size_t)M * N_D;  // 25.6M elements

  char* ws = (char*)d_ws;
  unsigned short* hA      = (unsigned short*)(ws);                  // 51.2 MB bf16
  unsigned*       colpack = (unsigned*)(ws + 51200000);             // 12.8 MB
  int*            row_ptr = (int*)(ws + 64000000);                  // 400 KB
  int*            cnts    = (int*)(ws + 64400128);                  // 400 KB
  int*            bsum    = (int*)(ws + 64800256);                  // 2 KB
  int*            bofs    = (int*)(ws + 64802816);                  // 2 KB
  int*            cntT    = (int*)(ws + 64805376);                  // 26.7 KB
  int*            pofsT   = (int*)(ws + 64832000);                  // 26.7 KB
  unsigned short* wt0     = (unsigned short*)(ws + 64858880);       // 128 KB
  unsigned short* wt1     = (unsigned short*)(ws + 64989952);       // 128 KB
  // d_out (102.4 MB fp32) hosts bf16/scratch buffers until the final spmm:
  unsigned short* hB   = (unsigned short*)d_out;                    // [0, 51.2 MB)
  unsigned short* hC   = (unsigned short*)d_out + n_feat;           // [51.2, 102.4 MB)
  int2*           part = (int2*)((char*)d_out + 51200000);          // [51.2, 76.8) build-only
  int*            cntc = (int*)((char*)d_out + 76800000);           // [76.8, 83.2) build-only

  const int Mb = (M + 255) / 256;           // 391
  const int sblocks = 4 * ((M + 7) / 8);    // 4 slices x (8 nodes per block)
  const int gblocks = (M + 127) / 128;      // 782
  const int rpg = (M + 7) / 8;              // 12500 rows per XCD group
  const unsigned gmagic = (unsigned)(((1ULL << 37) + rpg - 1) / (unsigned long long)rpg);

  // --- atomic-free CSR build, gemm0 overlapped with partition ---
  p0_kernel<<<NBLK + 512, 256, 0, stream>>>(rows, cntT, n_edges, gmagic,
                                            W0, W1, wt0, wt1);
  scan_one<<<1, 256, 0, stream>>>(cntT, pofsT, 8 * NBLK);
  fatpg_kernel<<<NBLK + gblocks, 256, 0, stream>>>(rows, cols, vals, pofsT, part,
                                                   n_edges, gmagic, x, wt0, hB, M);
  hist_kernel<<<8 * NCH, 256, 0, stream>>>(part, pofsT, cntc, M, rpg);
  sumcnt2_kernel<<<Mb, 256, 0, stream>>>(cntc, cnts, bsum, M, rpg);
  scan_one<<<1, 256, 0, stream>>>(bsum, bofs, Mb);
  apply_kernel<<<Mb, 256, 0, stream>>>(cnts, bofs, row_ptr, M);
  scatter3_kernel<<<8 * NCH, 256, 0, stream>>>(part, pofsT, row_ptr, cntc,
                                               colpack, M, rpg);

  // --- layer 0:  relu((0.5A)^2 hB)  [GEMM-first by associativity] ---
  spmm_slice<false, false><<<sblocks, 256, 0, stream>>>(hB, row_ptr, colpack, hA, M);
  spmm_slice<true,  false><<<sblocks, 256, 0, stream>>>(hA, row_ptr, colpack, hB, M);

  // --- layer 1:  (0.5A)^2 (h @ W1) ---
  gemm3_bf16<<<gblocks, 256, 0, stream>>>(hB, wt1, hC, M);
  spmm_slice<false, false><<<sblocks, 256, 0, stream>>>(hC, row_ptr, colpack, hA, M);
  spmm_slice<false, true ><<<sblocks, 256, 0, stream>>>(hA, row_ptr, colpack, d_out, M);
}

// Round 16
// 1058.783 us; speedup vs baseline: 1.6838x; 1.0167x over previous
//
#include <hip/hip_runtime.h>
#include <hip/hip_bf16.h>
#include <hip/hip_fp16.h>

#define N_D 256
#define NBLK 832      // partition/p0 grid; 16 chunks x 52 pblocks per group
#define CPB 52        // pblocks per chunk
#define NCH 16        // chunks per group
#define RPG_MAX 12512 // max rows per XCD group (LDS histogram size)
#define EPB 4096      // edges per block, contiguous (512-aligned)
#define PR 512        // edges per partition round

typedef __attribute__((ext_vector_type(8))) short bf16x8;
typedef __attribute__((ext_vector_type(4))) float f32x4;

// f32 -> bf16 round-to-nearest-even (finite inputs)
__device__ __forceinline__ unsigned short f2bf(float f) {
  union { float f; unsigned u; } c; c.f = f;
  unsigned u = c.u;
  return (unsigned short)((u + 0x7fffu + ((u >> 16) & 1u)) >> 16);
}
__device__ __forceinline__ float asf(unsigned u) {
  union { unsigned u; float f; } c; c.u = u;
  return c.f;
}
__device__ __forceinline__ int grp_of(int r, unsigned gmagic) {
  int g = (int)(((unsigned long long)(unsigned)r * gmagic) >> 37);
  return min(g, 7);
}
__device__ __forceinline__ unsigned packcv(int c, float vl) {
  const unsigned short hb = __half_as_ushort(__float2half_rn(vl * 0.5f));
  return ((unsigned)c << 15) | ((unsigned)hb >> 1);
}

// ---------- GEMM core: 128 rows/tile, 2 row-frags/wave x 16 col-frags --------
template <bool AF32>
__device__ __forceinline__ void gemm_core(
    const void* __restrict__ H, const unsigned short* __restrict__ WT,
    unsigned short* __restrict__ C, int M, int bid) {
  const int wave = threadIdx.x >> 6;
  const int lane = threadIdx.x & 63;
  const int m = lane & 15;
  const int p = lane >> 4;
  const int row0 = bid * 128 + wave * 32;

  f32x4 acc0[16], acc1[16];
#pragma unroll
  for (int i = 0; i < 16; ++i) {
    acc0[i] = (f32x4){0.f, 0.f, 0.f, 0.f};
    acc1[i] = (f32x4){0.f, 0.f, 0.f, 0.f};
  }

  const int r0 = row0 + m;
  const int r1 = row0 + 16 + m;
  const bool ok0 = r0 < M, ok1 = r1 < M;

  for (int k0 = 0; k0 < N_D; k0 += 32) {
    bf16x8 a0 = {0,0,0,0,0,0,0,0}, a1 = {0,0,0,0,0,0,0,0};
    if (AF32) {
      if (ok0) {
        const float* ap = (const float*)H + (size_t)r0 * N_D + k0 + p * 8;
        const float4 f0 = *reinterpret_cast<const float4*>(ap);
        const float4 f1 = *reinterpret_cast<const float4*>(ap + 4);
        a0[0]=f2bf(f0.x); a0[1]=f2bf(f0.y); a0[2]=f2bf(f0.z); a0[3]=f2bf(f0.w);
        a0[4]=f2bf(f1.x); a0[5]=f2bf(f1.y); a0[6]=f2bf(f1.z); a0[7]=f2bf(f1.w);
      }
      if (ok1) {
        const float* ap = (const float*)H + (size_t)r1 * N_D + k0 + p * 8;
        const float4 f0 = *reinterpret_cast<const float4*>(ap);
        const float4 f1 = *reinterpret_cast<const float4*>(ap + 4);
        a1[0]=f2bf(f0.x); a1[1]=f2bf(f0.y); a1[2]=f2bf(f0.z); a1[3]=f2bf(f0.w);
        a1[4]=f2bf(f1.x); a1[5]=f2bf(f1.y); a1[6]=f2bf(f1.z); a1[7]=f2bf(f1.w);
      }
    } else {
      if (ok0) a0 = *reinterpret_cast<const bf16x8*>(
          (const unsigned short*)H + (size_t)r0 * N_D + k0 + p * 8);
      if (ok1) a1 = *reinterpret_cast<const bf16x8*>(
          (const unsigned short*)H + (size_t)r1 * N_D + k0 + p * 8);
    }
#pragma unroll
    for (int nt = 0; nt < 16; ++nt) {
      const bf16x8 b = *reinterpret_cast<const bf16x8*>(
          WT + (size_t)(nt * 16 + m) * N_D + k0 + p * 8);
      acc0[nt] = __builtin_amdgcn_mfma_f32_16x16x32_bf16(a0, b, acc0[nt], 0, 0, 0);
      acc1[nt] = __builtin_amdgcn_mfma_f32_16x16x32_bf16(a1, b, acc1[nt], 0, 0, 0);
    }
  }

#pragma unroll
  for (int nt = 0; nt < 16; ++nt) {
    const int col = nt * 16 + m;
#pragma unroll
    for (int rr = 0; rr < 4; ++rr) {
      const int ra = row0 + p * 4 + rr;
      const int rb = ra + 16;
      if (ra < M) C[(size_t)ra * N_D + col] = f2bf(acc0[nt][rr]);
      if (rb < M) C[(size_t)rb * N_D + col] = f2bf(acc1[nt][rr]);
    }
  }
}

__global__ __launch_bounds__(256) void gemm3_f32(
    const float* __restrict__ H, const unsigned short* __restrict__ WT,
    unsigned short* __restrict__ C, int M) {
  gemm_core<true>(H, WT, C, M, blockIdx.x);
}
__global__ __launch_bounds__(256) void gemm3_bf16(
    const unsigned short* __restrict__ H, const unsigned short* __restrict__ WT,
    unsigned short* __restrict__ C, int M) {
  gemm_core<false>(H, WT, C, M, blockIdx.x);
}

// ---------- P0: per-(group,block-range) edge counts + weight transpose -------
// Block bid owns contiguous edges [bid*EPB, (bid+1)*EPB); int4-vectorized.
__global__ __launch_bounds__(256) void p0_kernel(
    const int* __restrict__ rows, int* __restrict__ cntT,
    int n_edges, unsigned gmagic,
    const float* __restrict__ W0, const float* __restrict__ W1,
    unsigned short* __restrict__ WT0, unsigned short* __restrict__ WT1) {
  if (blockIdx.x >= NBLK) {       // 512 trailing blocks: WT[n][k] = bf16(W[k][n])
    const int b = blockIdx.x - NBLK;
    const int w = b >> 8;
    const int k = b & 255;
    const int n = threadIdx.x;
    const float* W = w ? W1 : W0;
    unsigned short* WT = w ? WT1 : WT0;
    WT[(size_t)n * N_D + k] = f2bf(W[(size_t)k * N_D + n]);
    return;
  }
  __shared__ int l8[8];
  if (threadIdx.x < 8) l8[threadIdx.x] = 0;
  __syncthreads();
  const int e0 = blockIdx.x * EPB;
  const int e1 = min(n_edges, e0 + EPB);
  for (int e = e0 + threadIdx.x * 4; e < e1; e += 1024) {
    if (e + 3 < e1) {
      const int4 v = *reinterpret_cast<const int4*>(rows + e);
      atomicAdd(&l8[grp_of(v.x, gmagic)], 1);
      atomicAdd(&l8[grp_of(v.y, gmagic)], 1);
      atomicAdd(&l8[grp_of(v.z, gmagic)], 1);
      atomicAdd(&l8[grp_of(v.w, gmagic)], 1);
    } else {
      for (int k = 0; k < 4 && e + k < e1; ++k)
        atomicAdd(&l8[grp_of(rows[e + k], gmagic)], 1);
    }
  }
  __syncthreads();
  if (threadIdx.x < 8) cntT[threadIdx.x * NBLK + blockIdx.x] = l8[threadIdx.x];
}

// ---------- 256-thread exclusive scan; out[n] = total ----------
__global__ __launch_bounds__(256) void scan_one(
    const int* __restrict__ in, int* __restrict__ out, int n) {
  __shared__ int swsum[4];
  __shared__ int carry_sh;
  const int tid = threadIdx.x;
  const int lane = tid & 63;
  const int wid = tid >> 6;
  if (tid == 0) carry_sh = 0;
  __syncthreads();
  for (int base = 0; base < n; base += 1024) {
    const int i0 = base + tid * 4;
    int4 v = make_int4(0, 0, 0, 0);
    if (i0 + 3 < n) v = *reinterpret_cast<const int4*>(in + i0);
    else {
      if (i0     < n) v.x = in[i0];
      if (i0 + 1 < n) v.y = in[i0 + 1];
      if (i0 + 2 < n) v.z = in[i0 + 2];
    }
    const int s1 = v.x, s2 = s1 + v.y, s3 = s2 + v.z, s4 = s3 + v.w;
    int ws = s4;
#pragma unroll
    for (int off = 1; off < 64; off <<= 1) {
      int o = __shfl_up(ws, off, 64);
      if (lane >= off) ws += o;
    }
    if (lane == 63) swsum[wid] = ws;
    __syncthreads();
    if (wid == 0) {
      int t = (lane < 4) ? swsum[lane] : 0;
#pragma unroll
      for (int off = 1; off < 4; off <<= 1) {
        int o = __shfl_up(t, off, 64);
        if (lane >= off) t += o;
      }
      if (lane < 4) swsum[lane] = t;
    }
    __syncthreads();
    const int carry = carry_sh;
    const int tbase = carry + (wid ? swsum[wid - 1] : 0) + ws - s4;  // exclusive
    if (i0     < n) out[i0]     = tbase;
    if (i0 + 1 < n) out[i0 + 1] = tbase + s1;
    if (i0 + 2 < n) out[i0 + 2] = tbase + s2;
    if (i0 + 3 < n) out[i0 + 3] = tbase + s3;
    __syncthreads();
    if (tid == 0) carry_sh = carry + swsum[3];
    __syncthreads();
  }
  if (tid == 0) out[n] = carry_sh;
}

// ---------- P1: LDS-staged radix partition into [group][block] segments ------
// Per 512-edge round: classify into 8 per-group LDS buffers, then flush each
// buffer as a dense coalesced burst. Converts 8-way scattered writes into
// sequential full-line writes per group segment.
__global__ __launch_bounds__(256) void partition_kernel(
    const int* __restrict__ rows, const int* __restrict__ cols,
    const float* __restrict__ vals, const int* __restrict__ pofsT,
    int2* __restrict__ part, int n_edges, unsigned gmagic) {
  __shared__ int lofs[8];
  __shared__ int lcnt[8];
  __shared__ int2 lbuf[8][PR];   // 32 KB
  const int tid = threadIdx.x;
  const int bid = blockIdx.x;
  if (tid < 8) lofs[tid] = pofsT[tid * NBLK + bid];
  const int e0 = bid * EPB;
  const int e1 = min(n_edges, e0 + EPB);
  for (int base = e0; base < e1; base += PR) {
    if (tid < 8) lcnt[tid] = 0;
    __syncthreads();
    const int e = base + tid * 2;
    if (e < e1) {
      int2 rr, cc; float2 vv;
      const bool two = (e + 1 < e1);
      if (two) {
        rr = *reinterpret_cast<const int2*>(rows + e);
        cc = *reinterpret_cast<const int2*>(cols + e);
        vv = *reinterpret_cast<const float2*>(vals + e);
      } else {
        rr.x = rows[e]; cc.x = cols[e]; vv.x = vals[e];
      }
      {
        const int g = grp_of(rr.x, gmagic);
        const int slot = atomicAdd(&lcnt[g], 1);
        lbuf[g][slot] = make_int2(rr.x, (int)packcv(cc.x, vv.x));
      }
      if (two) {
        const int g = grp_of(rr.y, gmagic);
        const int slot = atomicAdd(&lcnt[g], 1);
        lbuf[g][slot] = make_int2(rr.y, (int)packcv(cc.y, vv.y));
      }
    }
    __syncthreads();
    // flush: dense coalesced copy per group
    for (int g = 0; g < 8; ++g) {
      const int c = lcnt[g];
      const int o = lofs[g];
      for (int i = tid; i < c; i += 256) part[o + i] = lbuf[g][i];
    }
    __syncthreads();               // all lbuf reads complete before next round
    if (tid < 8) lofs[tid] += lcnt[tid];
  }
}

// ---------- P2: per-(group,chunk) row histogram in LDS -> cntc (NO atomics) --
__global__ __launch_bounds__(256) void hist_kernel(
    const int2* __restrict__ part, const int* __restrict__ pofsT,
    int* __restrict__ cntc, int M, int rpg) {
  const int g = blockIdx.x & 7;
  const int b = blockIdx.x >> 3;
  const int r0 = g * rpg;
  const int nr = min(rpg, M - r0);
  __shared__ int lh[RPG_MAX];
  for (int r = threadIdx.x; r < nr; r += 256) lh[r] = 0;
  __syncthreads();
  const int s0 = pofsT[g * NBLK + b * CPB];
  const int s1 = pofsT[g * NBLK + (b + 1) * CPB];
  for (int i = s0 + threadIdx.x; i < s1; i += 256) {
    atomicAdd(&lh[part[i].x - r0], 1);   // LDS atomic, random over 12.5K
  }
  __syncthreads();
  int* dst = cntc + (size_t)(g * NCH + b) * rpg;
  for (int r = threadIdx.x; r < nr; r += 256) dst[r] = lh[r];  // coalesced
}

// ---------- P3a: cnts[r] = sum over chunks; cntc -> exclusive chunk prefix ---
__global__ __launch_bounds__(256) void sumcnt2_kernel(
    int* __restrict__ cntc, int* __restrict__ cnts,
    int* __restrict__ bsum, int M, int rpg) {
  __shared__ int wred[4];
  const int i = blockIdx.x * 256 + threadIdx.x;
  int s = 0;
  if (i < M) {
    const int g = i / rpg;
    const int rr = i - g * rpg;
    int* base = cntc + (size_t)g * NCH * rpg + rr;
#pragma unroll
    for (int b = 0; b < NCH; ++b) {
      const int c = base[(size_t)b * rpg];
      base[(size_t)b * rpg] = s;          // exclusive prefix along chunks
      s += c;
    }
    cnts[i] = s;
  }
  int t = s;
#pragma unroll
  for (int off = 32; off; off >>= 1) t += __shfl_down(t, off, 64);
  if ((threadIdx.x & 63) == 0) wred[threadIdx.x >> 6] = t;
  __syncthreads();
  if (threadIdx.x == 0) bsum[blockIdx.x] = wred[0] + wred[1] + wred[2] + wred[3];
}

// ---------- P3c: row_ptr = bofs[chunk] + intra-chunk exclusive scan ----------
__global__ __launch_bounds__(256) void apply_kernel(
    const int* __restrict__ cnts, const int* __restrict__ bofs,
    int* __restrict__ row_ptr, int M) {
  __shared__ int wsum[4];
  const int tid = threadIdx.x;
  const int lane = tid & 63;
  const int wid = tid >> 6;
  const int i = blockIdx.x * 256 + tid;
  const int v = (i < M) ? cnts[i] : 0;
  int s = v;
#pragma unroll
  for (int off = 1; off < 64; off <<= 1) {
    int o = __shfl_up(s, off, 64);
    if (lane >= off) s += o;
  }
  if (lane == 63) wsum[wid] = s;
  __syncthreads();
  int add = 0;
  for (int k = 0; k < wid; ++k) add += wsum[k];
  const int excl = bofs[blockIdx.x] + add + s - v;
  if (i < M) row_ptr[i] = excl;
  if (i == M) row_ptr[M] = bofs[gridDim.x];
}

// ---------- P4: scatter via LDS cursors (NO global atomics) ----------
__global__ __launch_bounds__(256) void scatter3_kernel(
    const int2* __restrict__ part, const int* __restrict__ pofsT,
    const int* __restrict__ row_ptr, const int* __restrict__ cntc,
    unsigned* __restrict__ colpack, int M, int rpg) {
  const int g = blockIdx.x & 7;
  const int b = blockIdx.x >> 3;
  const int r0 = g * rpg;
  const int nr = min(rpg, M - r0);
  __shared__ int lc[RPG_MAX];
  const int* pfx = cntc + (size_t)(g * NCH + b) * rpg;
  for (int r = threadIdx.x; r < nr; r += 256)
    lc[r] = row_ptr[r0 + r] + pfx[r];
  __syncthreads();
  const int s0 = pofsT[g * NBLK + b * CPB];
  const int s1 = pofsT[g * NBLK + (b + 1) * CPB];
  for (int i = s0 + threadIdx.x; i < s1; i += 256) {
    const int2 rv = part[i];
    const int pos = atomicAdd(&lc[rv.x - r0], 1);   // LDS atomic
    colpack[pos] = (unsigned)rv.y;                  // XCD-local, L2-merged
  }
}

// ---------- SpMM, feature-sliced (round-6 config: MLP 8, inline decode) ------
template <bool RELU, bool F32OUT>
__global__ __launch_bounds__(256) void spmm_slice(
    const unsigned short* __restrict__ hin, const int* __restrict__ row_ptr,
    const unsigned* __restrict__ colpack, void* __restrict__ hout,
    int n_nodes) {
  const int slice = blockIdx.x & 3;
  const int lane = threadIdx.x & 63;
  const int half = lane >> 5;
  const int sub  = lane & 31;
  const int wgid = ((blockIdx.x >> 2) * 256 + threadIdx.x) >> 6;  // node-pair id
  const int node = wgid * 2 + half;
  const bool ok = node < n_nodes;
  int start = 0, end = 0;
  if (ok) { start = row_ptr[node]; end = row_ptr[node + 1]; }

  const unsigned* __restrict__ hinw = reinterpret_cast<const unsigned*>(hin);
  const int fofs = slice * 32 + sub;       // uint index within a 128-uint row
  const int sbase = half << 5;

  float acc0 = 0.f, acc1 = 0.f;

  for (int base = start; base < end; base += 32) {
    const int cnt = min(32, end - base);
    unsigned u = 0;                        // u=0 -> (col=0, val=0) dummy
    if (base + sub < end) u = __builtin_nontemporal_load(&colpack[base + sub]);
    for (int t = 0; t < cnt; t += 8) {
      unsigned hv[8];
      float v[8];
#pragma unroll
      for (int j = 0; j < 8; ++j) {
        const unsigned ue = (unsigned)__shfl((int)u, sbase + t + j, 64);
        const int c = (int)(ue >> 15);
        v[j] = __half2float(__ushort_as_half((unsigned short)(ue << 1)));
        hv[j] = hinw[(size_t)c * 128 + fofs];   // 8 independent 4B gathers
      }
#pragma unroll
      for (int j = 0; j < 8; ++j) {
        acc0 += v[j] * asf(hv[j] << 16);
        acc1 += v[j] * asf(hv[j] & 0xffff0000u);
      }
    }
  }
  if (ok) {
    if (RELU) { acc0 = fmaxf(acc0, 0.f); acc1 = fmaxf(acc1, 0.f); }
    if (F32OUT) {
      reinterpret_cast<float2*>(hout)[(size_t)node * 128 + fofs] =
          make_float2(acc0, acc1);
    } else {
      reinterpret_cast<unsigned*>(hout)[(size_t)node * 128 + fofs] =
          (unsigned)f2bf(acc0) | ((unsigned)f2bf(acc1) << 16);
    }
  }
}

extern "C" void kernel_launch(void* const* d_in, const int* in_sizes, int n_in,
                              void* d_out, int out_size, void* d_ws, size_t ws_size,
                              hipStream_t stream) {
  const float* x    = (const float*)d_in[0];
  const float* vals = (const float*)d_in[1];
  const float* W0   = (const float*)d_in[2];
  const float* W1   = (const float*)d_in[3];
  const int*   rows = (const int*)d_in[4];
  const int*   cols = (const int*)d_in[5];

  const int n_edges = in_sizes[1];
  const int M = in_sizes[0] / N_D;        // 100000
  const size_t n_feat = (size_t)M * N_D;  // 25.6M elements

  char* ws = (char*)d_ws;
  unsigned short* hA      = (unsigned short*)(ws);                  // 51.2 MB bf16
  unsigned*       colpack = (unsigned*)(ws + 51200000);             // 12.8 MB
  int*            row_ptr = (int*)(ws + 64000000);                  // 400 KB
  int*            cnts    = (int*)(ws + 64400128);                  // 400 KB
  int*            bsum    = (int*)(ws + 64800256);                  // 2 KB
  int*            bofs    = (int*)(ws + 64802816);                  // 2 KB
  int*            cntT    = (int*)(ws + 64805376);                  // 26.7 KB
  int*            pofsT   = (int*)(ws + 64832000);                  // 26.7 KB
  unsigned short* wt0     = (unsigned short*)(ws + 64858880);       // 128 KB
  unsigned short* wt1     = (unsigned short*)(ws + 64989952);       // 128 KB
  // d_out (102.4 MB fp32) hosts bf16/scratch buffers until the final spmm:
  unsigned short* hB   = (unsigned short*)d_out;                    // [0, 51.2 MB)
  unsigned short* hC   = (unsigned short*)d_out + n_feat;           // [51.2, 102.4 MB)
  int2*           part = (int2*)((char*)d_out + 51200000);          // [51.2, 76.8) build-only
  int*            cntc = (int*)((char*)d_out + 76800000);           // [76.8, 83.2) build-only

  const int Mb = (M + 255) / 256;           // 391
  const int sblocks = 4 * ((M + 7) / 8);    // 4 slices x (8 nodes per block)
  const int gblocks = (M + 127) / 128;      // 782
  const int rpg = (M + 7) / 8;              // 12500 rows per XCD group
  const unsigned gmagic = (unsigned)(((1ULL << 37) + rpg - 1) / (unsigned long long)rpg);

  // --- atomic-free CSR build (all streaming kernels standalone) ---
  p0_kernel<<<NBLK + 512, 256, 0, stream>>>(rows, cntT, n_edges, gmagic,
                                            W0, W1, wt0, wt1);
  scan_one<<<1, 256, 0, stream>>>(cntT, pofsT, 8 * NBLK);
  gemm3_f32<<<gblocks, 256, 0, stream>>>(x, wt0, hB, M);   // hB = x@W0 (indep)
  partition_kernel<<<NBLK, 256, 0, stream>>>(rows, cols, vals, pofsT, part,
                                             n_edges, gmagic);
  hist_kernel<<<8 * NCH, 256, 0, stream>>>(part, pofsT, cntc, M, rpg);
  sumcnt2_kernel<<<Mb, 256, 0, stream>>>(cntc, cnts, bsum, M, rpg);
  scan_one<<<1, 256, 0, stream>>>(bsum, bofs, Mb);
  apply_kernel<<<Mb, 256, 0, stream>>>(cnts, bofs, row_ptr, M);
  scatter3_kernel<<<8 * NCH, 256, 0, stream>>>(part, pofsT, row_ptr, cntc,
                                               colpack, M, rpg);

  // --- layer 0:  relu((0.5A)^2 hB)  [GEMM-first by associativity] ---
  spmm_slice<false, false><<<sblocks, 256, 0, stream>>>(hB, row_ptr, colpack, hA, M);
  spmm_slice<true,  false><<<sblocks, 256, 0, stream>>>(hA, row_ptr, colpack, hB, M);

  // --- layer 1:  (0.5A)^2 (h @ W1) ---
  gemm3_bf16<<<gblocks, 256, 0, stream>>>(hB, wt1, hC, M);
  spmm_slice<false, false><<<sblocks, 256, 0, stream>>>(hC, row_ptr, colpack, hA, M);
  spmm_slice<false, true ><<<sblocks, 256, 0, stream>>>(hA, row_ptr, colpack, d_out, M);
}